// Round 15
// baseline (238.759 us; speedup 1.0000x reference)
//
#include <hip/hip_runtime.h>
#include <hip/hip_fp16.h>

#define L_SEQ 4096
#define THR_GAP 0.08f
#define FIX_CAP 1536

typedef _Float16 f16x8 __attribute__((ext_vector_type(8)));
typedef _Float16 f16x4 __attribute__((ext_vector_type(4)));
typedef float f32x4 __attribute__((ext_vector_type(4)));

typedef __attribute__((address_space(3))) void lds_void;
typedef __attribute__((address_space(1))) void glob_void;
__device__ __forceinline__ void gload16(const _Float16* g, _Float16* l) {
  __builtin_amdgcn_global_load_lds((const glob_void*)g, (lds_void*)l, 16, 0, 0);
}

// ---------------- converts ----------------
__global__ __launch_bounds__(256)
void cvt_f16(const float* __restrict__ in, _Float16* __restrict__ out_) {
  int i = blockIdx.x * 256 + threadIdx.x;
  float4 v = ((const float4*)in)[i];
  f16x4 h;
  h[0] = (_Float16)v.x; h[1] = (_Float16)v.y;
  h[2] = (_Float16)v.z; h[3] = (_Float16)v.w;
  *(f16x4*)(out_ + (size_t)i * 4) = h;
}

__global__ __launch_bounds__(256)
void cvt_tr_f16(const float* __restrict__ W, _Float16* __restrict__ WT) {
  __shared__ _Float16 tile[32][33];
  const int bx = blockIdx.x * 32, by = blockIdx.y * 32;
  const int tx = threadIdx.x & 31, ty = threadIdx.x >> 5;
  #pragma unroll
  for (int i = ty; i < 32; i += 8)
    tile[i][tx] = (_Float16)W[(size_t)(by + i) * 1024 + bx + tx];
  __syncthreads();
  #pragma unroll
  for (int i = ty; i < 32; i += 8)
    WT[(size_t)(bx + i) * 1024 + by + tx] = tile[tx][i];
}

// rotT_f16[c][d] = rot[d][c],  c = nh*32+rb, 64x64
__global__ __launch_bounds__(256)
void cvt_rotT(const float* __restrict__ rot, _Float16* __restrict__ rotT) {
  const int tid = threadIdx.x;
  const int c = tid >> 2, d0 = (tid & 3) * 16;
  #pragma unroll
  for (int k = 0; k < 16; ++k)
    rotT[c * 64 + d0 + k] = (_Float16)rot[(d0 + k) * 64 + c];
}

// ---------------- f16 MFMA GEMM, dbuf + counted vmcnt: C = A * BT^T ----------------
// MODE 0: C row-major f32; MODE 1: scatter f16 to [n][l][d]
template<int MODE>
__global__ __launch_bounds__(256)
void gemm_f16(const _Float16* __restrict__ A, const _Float16* __restrict__ BT,
              float* __restrict__ C, int M, int K, int Nn) {
  __shared__ _Float16 As[2][128 * 64];
  __shared__ _Float16 Bs[2][128 * 64];
  const int tid = threadIdx.x;
  const int lane = tid & 63, wid = tid >> 6;
  const int wr = wid >> 1, wc = wid & 1;
  const int f = blockIdx.x;
  const int u = (f & 7) * 64 + (f >> 3);
  const int row0 = (u >> 3) * 128, col0 = (u & 7) * 128;

  f32x4 acc[4][4];
  #pragma unroll
  for (int i = 0; i < 4; ++i)
    #pragma unroll
    for (int j = 0; j < 4; ++j)
      acc[i][j] = (f32x4){0.f, 0.f, 0.f, 0.f};

  const int srow = (lane >> 3);
  const int scol = ((lane & 7) ^ srow) * 8;
  const _Float16* ga = A + (size_t)(row0 + wid * 32 + srow) * K + scol;
  const _Float16* gb = BT + (size_t)(col0 + wid * 32 + srow) * K + scol;
  const int lbase = (wid * 32) * 64;
  const int fr = lane & 15, g = lane >> 4;

#define STAGE_F16(buf, k0) do {                                          \
    _Pragma("unroll")                                                    \
    for (int i_ = 0; i_ < 4; ++i_) {                                     \
      gload16(ga + (k0) + (size_t)i_ * 8 * K, &As[buf][lbase + i_ * 8 * 64]); \
      gload16(gb + (k0) + (size_t)i_ * 8 * K, &Bs[buf][lbase + i_ * 8 * 64]); \
    }                                                                    \
  } while (0)

  STAGE_F16(0, 0);

  const int NT = K / 64;
  for (int t = 0; t < NT; ++t) {
    const int cur = t & 1, nxt = cur ^ 1;
    if (t + 1 < NT) {
      STAGE_F16(nxt, (size_t)(t + 1) * 64);
      asm volatile("s_waitcnt vmcnt(8)" ::: "memory");
    } else {
      asm volatile("s_waitcnt vmcnt(0)" ::: "memory");
    }
    __builtin_amdgcn_s_barrier();
    __builtin_amdgcn_sched_barrier(0);

    f16x8 af[4][2], bf[4][2];
    #pragma unroll
    for (int fi = 0; fi < 4; ++fi) {
      const int ra = (wr * 64 + fi * 16 + fr) * 64;
      const int rb = (wc * 64 + fi * 16 + fr) * 64;
      #pragma unroll
      for (int ks = 0; ks < 2; ++ks) {
        const int ko = (ks * 32 + g * 8) ^ ((fr & 7) * 8);
        af[fi][ks] = *(const f16x8*)(&As[cur][ra + ko]);
        bf[fi][ks] = *(const f16x8*)(&Bs[cur][rb + ko]);
      }
    }
    #pragma unroll
    for (int ks = 0; ks < 2; ++ks)
      #pragma unroll
      for (int fi = 0; fi < 4; ++fi)
        #pragma unroll
        for (int fj = 0; fj < 4; ++fj)
          acc[fi][fj] = __builtin_amdgcn_mfma_f32_16x16x32_f16(
              af[fi][ks], bf[fj][ks], acc[fi][fj], 0, 0, 0);
    __builtin_amdgcn_s_barrier();
    __builtin_amdgcn_sched_barrier(0);
  }
#undef STAGE_F16

  _Float16* Ch = (_Float16*)C;
  #pragma unroll
  for (int fi = 0; fi < 4; ++fi) {
    #pragma unroll
    for (int fj = 0; fj < 4; ++fj) {
      const int col = col0 + wc * 64 + fj * 16 + fr;
      #pragma unroll
      for (int r = 0; r < 4; ++r) {
        const int row = row0 + wr * 64 + fi * 16 + g * 4 + r;
        if (MODE == 0) {
          C[(size_t)row * Nn + col] = acc[fi][fj][r];
        } else {
          int b = row >> 12, l = row & 4095;
          int h = col >> 6, d = col & 63;
          Ch[(((size_t)(b * 16 + h) * L_SEQ) + l) * 64 + d] = (_Float16)acc[fi][fj][r];
        }
      }
    }
  }
}

// ---------------- MFMA LSH hashing + lane-local top-2 argmax ----------------
// block = 4 waves; wave handles 64 consecutive tokens of batch n.
__global__ __launch_bounds__(256, 2)
void lsh_hash3(const _Float16* __restrict__ qkh, const _Float16* __restrict__ rotT,
               unsigned char* __restrict__ bucket,
               unsigned int* __restrict__ lists, unsigned int* __restrict__ cnt) {
  __shared__ float buf[4][32][67];   // wave-private transpose tile
  const int tid = threadIdx.x, lane = tid & 63, wv = tid >> 6;
  const int fr = lane & 15, g = lane >> 4;
  const int bid = blockIdx.x;               // 512
  const int n = bid >> 4;
  const int l0 = (bid & 15) * 256 + wv * 64;
  const int h = n & 15;

  // B fragments: rotT row (= rotation output column c = nh*32+rb), k = d
  f16x8 bf[4][2];
  #pragma unroll
  for (int fj = 0; fj < 4; ++fj)
    #pragma unroll
    for (int ks = 0; ks < 2; ++ks)
      bf[fj][ks] = *(const f16x8*)&rotT[(fj * 16 + fr) * 64 + ks * 32 + g * 8];

  f32x4 acc[4][4];
  #pragma unroll
  for (int i = 0; i < 4; ++i)
    #pragma unroll
    for (int j = 0; j < 4; ++j)
      acc[i][j] = (f32x4){0.f, 0.f, 0.f, 0.f};

  const _Float16* qbase = qkh + ((size_t)n * L_SEQ + l0) * 64;
  #pragma unroll
  for (int fi = 0; fi < 4; ++fi) {
    f16x8 a0 = *(const f16x8*)(qbase + (size_t)(fi * 16 + fr) * 64 + g * 8);
    f16x8 a1 = *(const f16x8*)(qbase + (size_t)(fi * 16 + fr) * 64 + 32 + g * 8);
    #pragma unroll
    for (int fj = 0; fj < 4; ++fj) {
      acc[fi][fj] = __builtin_amdgcn_mfma_f32_16x16x32_f16(a0, bf[fj][0], acc[fi][fj], 0, 0, 0);
      acc[fi][fj] = __builtin_amdgcn_mfma_f32_16x16x32_f16(a1, bf[fj][1], acc[fi][fj], 0, 0, 0);
    }
  }

#define INS(vv, ii) do {                                                  \
    float v_ = (vv); int i_ = (ii);                                       \
    if (v_ > b1v || (v_ == b1v && i_ < b1i)) { b2v = b1v; b1v = v_; b1i = i_; } \
    else b2v = fmaxf(b2v, v_);                                            \
  } while (0)

  // two passes of 32 tokens; lane = (token, round) scans its 32 cols streaming
  // from LDS (no register staging array -> no spill; INS is order-independent)
  #pragma unroll 1
  for (int p = 0; p < 2; ++p) {
    #pragma unroll
    for (int q = 0; q < 2; ++q) {         // fi = 2p+q -> local rows q*16+g*4+r
      #pragma unroll
      for (int fj = 0; fj < 4; ++fj)
        #pragma unroll
        for (int r = 0; r < 4; ++r)
          buf[wv][q * 16 + g * 4 + r][fj * 16 + fr] = acc[2 * p + q][fj][r];
    }
    const int tok = lane & 31, nh = lane >> 5;
    float b1v = -3.0e38f; int b1i = 0; float b2v = -3.0e38f;
    #pragma unroll 8
    for (int j = 0; j < 32; ++j) {
      float v = buf[wv][tok][nh * 32 + j];
      INS(v, j);
      INS(-v, 32 + j);
    }
    const float gap = b1v - b2v;
    const int obi = __shfl_xor(b1i, 32, 64);
    const float ogap = __shfl_xor(gap, 32, 64);
    if (nh == 0) {
      const int t = l0 + p * 32 + tok;
      bucket[((size_t)n * 2 + 0) * L_SEQ + t] = (unsigned char)b1i;
      bucket[((size_t)n * 2 + 1) * L_SEQ + t] = (unsigned char)obi;
      if (fminf(gap, ogap) < THR_GAP) {
        unsigned int pos = atomicAdd(&cnt[h], 1u);
        if (pos < FIX_CAP)
          lists[(size_t)h * FIX_CAP + pos] = ((unsigned int)n << 12) | (unsigned int)t;
      }
    }
  }
#undef INS
}

// ---------------- fixup phase A: K-split skinny GEMM partials ----------------
__global__ __launch_bounds__(256)
void lsh_fix_gemm(const float* __restrict__ x, const float* __restrict__ Wqk,
                  const unsigned int* __restrict__ lists,
                  const unsigned int* __restrict__ cnt,
                  float* __restrict__ qkfixp) {
  __shared__ float As[32][65];
  __shared__ float Bs[32][64];
  __shared__ int rowIdx[64];
  const int h = blockIdx.x;
  const int rt = blockIdx.y;
  const int ks = blockIdx.z;
  const unsigned int nfix = min(cnt[h], (unsigned int)FIX_CAP);
  if ((unsigned int)(rt * 64) >= nfix) return;
  const int tid = threadIdx.x;
  if (tid < 64) {
    unsigned int i = (unsigned int)(rt * 64 + tid);
    if (i >= nfix) i = nfix - 1;
    unsigned int ent = lists[(size_t)h * FIX_CAP + i];
    rowIdx[tid] = (int)((ent >> 12) >> 4) * 4096 + (int)(ent & 4095);
  }
  __syncthreads();
  float acc[4][4] = {{0.f}};
  const int tx = tid & 15, ty = tid >> 4;
  const int am = tid >> 2, ae = (tid & 3) * 8;
  const int be = tid >> 3, bd = (tid & 7) * 8;
  const size_t arow = (size_t)rowIdx[am] * 1024;
  const int kbeg = ks * 256, kend = kbeg + 256;

  float4 ra0, ra1, rb0, rb1;
  {
    const float* xr = x + arow + kbeg + ae;
    ra0 = *(const float4*)xr; ra1 = *(const float4*)(xr + 4);
    const float* wr = Wqk + (size_t)(kbeg + be) * 1024 + h * 64 + bd;
    rb0 = *(const float4*)wr; rb1 = *(const float4*)(wr + 4);
  }
  for (int k0 = kbeg; k0 < kend; k0 += 32) {
    As[ae + 0][am] = ra0.x; As[ae + 1][am] = ra0.y;
    As[ae + 2][am] = ra0.z; As[ae + 3][am] = ra0.w;
    As[ae + 4][am] = ra1.x; As[ae + 5][am] = ra1.y;
    As[ae + 6][am] = ra1.z; As[ae + 7][am] = ra1.w;
    *(float4*)&Bs[be][bd] = rb0;
    *(float4*)&Bs[be][bd + 4] = rb1;
    __syncthreads();
    if (k0 + 32 < kend) {
      const float* xr = x + arow + (k0 + 32) + ae;
      ra0 = *(const float4*)xr; ra1 = *(const float4*)(xr + 4);
      const float* wr = Wqk + (size_t)(k0 + 32 + be) * 1024 + h * 64 + bd;
      rb0 = *(const float4*)wr; rb1 = *(const float4*)(wr + 4);
    }
    #pragma unroll
    for (int k = 0; k < 32; ++k) {
      float a[4], b[4];
      #pragma unroll
      for (int j = 0; j < 4; ++j) a[j] = As[k][ty * 4 + j];
      #pragma unroll
      for (int j = 0; j < 4; ++j) b[j] = Bs[k][tx * 4 + j];
      #pragma unroll
      for (int i = 0; i < 4; ++i)
        #pragma unroll
        for (int j = 0; j < 4; ++j)
          acc[i][j] += a[i] * b[j];
    }
    __syncthreads();
  }
  #pragma unroll
  for (int i = 0; i < 4; ++i) {
    int m = rt * 64 + ty * 4 + i;
    float* dst = qkfixp + (((size_t)ks * 16 + h) * FIX_CAP + m) * 64 + tx * 4;
    dst[0] = acc[i][0]; dst[1] = acc[i][1];
    dst[2] = acc[i][2]; dst[3] = acc[i][3];
  }
}

// ---------------- fixup phase B: sum K-partials, rotations, exact argmax --------
__global__ __launch_bounds__(256)
void lsh_fix_rot(const float* __restrict__ qkfixp, const float* __restrict__ rot,
                 const unsigned int* __restrict__ lists,
                 const unsigned int* __restrict__ cnt,
                 unsigned char* __restrict__ bucket) {
  __shared__ float rotL[4096];
  __shared__ float qkL[4][64];
  const int h = blockIdx.x & 15;
  const int bg = blockIdx.x >> 4;
  const int tid = threadIdx.x, lane = tid & 63, wv = tid >> 6;
  for (int i = tid; i < 4096; i += 256) rotL[i] = rot[i];
  __syncthreads();
  const unsigned int nfix = min(cnt[h], (unsigned int)FIX_CAP);
  for (unsigned int i = (unsigned int)(bg * 4 + wv); i < nfix; i += 64) {
    unsigned int ent = lists[(size_t)h * FIX_CAP + i];
    const int nn = (int)(ent >> 12), ll = (int)(ent & 4095);
    float s0 = qkfixp[(((size_t)0 * 16 + h) * FIX_CAP + i) * 64 + lane];
    float s1 = qkfixp[(((size_t)1 * 16 + h) * FIX_CAP + i) * 64 + lane];
    float s2 = qkfixp[(((size_t)2 * 16 + h) * FIX_CAP + i) * 64 + lane];
    float s3 = qkfixp[(((size_t)3 * 16 + h) * FIX_CAP + i) * 64 + lane];
    qkL[wv][lane] = ((s0 + s1) + s2) + s3;
    asm volatile("s_waitcnt vmcnt(0) lgkmcnt(0)" ::: "memory");
    float v = 0.f;
    #pragma unroll 16
    for (int d = 0; d < 64; ++d)
      v += qkL[wv][d] * rotL[d * 64 + lane];
    const int r = lane & 31;
    float vneg = -v;
    float bv; int bi;
    if (vneg > v) { bv = vneg; bi = 32 + r; } else { bv = v; bi = r; }
    #pragma unroll
    for (int off = 1; off < 32; off <<= 1) {
      float ov = __shfl_xor(bv, off, 64);
      int oi = __shfl_xor(bi, off, 64);
      if (ov > bv || (ov == bv && oi < bi)) { bv = ov; bi = oi; }
    }
    if (r == 0) {
      int hr = lane >> 5;
      bucket[((size_t)(nn * 2 + hr)) * L_SEQ + ll] = (unsigned char)bi;
    }
  }
}

// ---------------- parallel stable counting sort per (n, round) ----------------
__global__ __launch_bounds__(256)
void lsh_sort(const unsigned char* __restrict__ bucket, unsigned int* __restrict__ st) {
  __shared__ unsigned short cnt[64][257];
  __shared__ unsigned int bstart[64];
  __shared__ unsigned char bkt[4096];
  const int nr = blockIdx.x;
  const int tid = threadIdx.x;
  const unsigned char* bsrc = bucket + (size_t)nr * L_SEQ;
  for (int i = tid; i < 1024; i += 256)
    ((unsigned int*)bkt)[i] = ((const unsigned int*)bsrc)[i];
  #pragma unroll
  for (int b = 0; b < 64; ++b) cnt[b][tid] = 0;
  __syncthreads();
  uint4 wv = ((const uint4*)bkt)[tid];
  unsigned int wsg[4] = {wv.x, wv.y, wv.z, wv.w};
  #pragma unroll
  for (int k = 0; k < 16; ++k) {
    int b = (wsg[k >> 2] >> ((k & 3) * 8)) & 63;
    cnt[b][tid]++;
  }
  __syncthreads();
  if (tid < 64) {
    const int b = tid;
    unsigned int run = 0;
    for (int t = 0; t < 256; ++t) {
      unsigned int c = cnt[b][t];
      cnt[b][t] = (unsigned short)run;
      run += c;
    }
    unsigned int incl = run;
    #pragma unroll
    for (int off = 1; off < 64; off <<= 1) {
      unsigned int up = (unsigned int)__shfl_up((int)incl, off);
      if (tid >= off) incl += up;
    }
    bstart[b] = incl - run;
  }
  __syncthreads();
  const int n = nr >> 1, r = nr & 1;
  unsigned int* dst = st + (size_t)n * 8192 + (size_t)r * 4096;
  #pragma unroll
  for (int k = 0; k < 16; ++k) {
    int b = (wsg[k >> 2] >> ((k & 3) * 8)) & 63;
    unsigned int idx = bstart[b] + cnt[b][tid];
    cnt[b][tid]++;
    dst[idx] = (unsigned int)(tid * 16 + k);
  }
}

// ---------------- MFMA chunked local attention (f16 qk gather) ----------------
__global__ __launch_bounds__(256)
void lsh_attn_mfma(const _Float16* __restrict__ qkh, const _Float16* __restrict__ vh,
                   const unsigned int* __restrict__ st,
                   _Float16* __restrict__ o, float* __restrict__ logits) {
  __shared__ _Float16 Kl[128 * 64];
  __shared__ _Float16 Vt[64 * 128];
  __shared__ _Float16 Pl[64 * 128];
  __shared__ float rsqs[128];
  __shared__ float partial[256];
  __shared__ int posl[128];

  const int tid = threadIdx.x;
  const int lane = tid & 63, wid = tid >> 6;
  const int fr = lane & 15, g = lane >> 4;
  const int c = blockIdx.x, n = blockIdx.y;
  const int cprev = (c + 127) & 127;

  if (tid < 128) {
    int p = (tid < 64) ? (c * 64 + tid) : (cprev * 64 + (tid - 64));
    posl[tid] = (int)st[(size_t)n * 8192 + p];
  }
  __syncthreads();

  {
    const int j = tid >> 1, h = tid & 1;
    const int gpos = posl[j];
    const f16x8* srcK = (const f16x8*)(qkh + ((size_t)n * L_SEQ + gpos) * 64 + h * 32);
    const f16x8* srcV = (const f16x8*)(vh + ((size_t)n * L_SEQ + gpos) * 64 + h * 32);
    float ss = 0.f;
    #pragma unroll
    for (int i = 0; i < 4; ++i) {
      f16x8 kv = srcK[i];
      f16x8 vv4 = srcV[i];
      #pragma unroll
      for (int e = 0; e < 8; ++e) {
        float xv = (float)kv[e];
        ss += xv * xv;
        int d = h * 32 + i * 8 + e;
        Vt[d * 128 + (j ^ ((d & 7) << 3))] = vv4[e];
      }
      int ch = h * 4 + i;
      *(f16x8*)(&Kl[j * 64 + ((ch ^ (j & 7)) * 8)]) = kv;
    }
    partial[tid] = ss;
  }
  __syncthreads();
  if (tid < 128)
    rsqs[tid] = rsqrtf(fmaxf(partial[tid * 2] + partial[tid * 2 + 1], 1e-12f));
  __syncthreads();

  const int q0 = wid * 16;
  f32x4 acc[8];
  #pragma unroll
  for (int t = 0; t < 8; ++t) acc[t] = (f32x4){0.f, 0.f, 0.f, 0.f};
  f16x8 aq[2];
  #pragma unroll
  for (int ks = 0; ks < 2; ++ks)
    aq[ks] = *(const f16x8*)&Kl[(q0 + fr) * 64 + (((ks * 4 + g) ^ (fr & 7)) * 8)];
  #pragma unroll
  for (int t = 0; t < 8; ++t) {
    #pragma unroll
    for (int ks = 0; ks < 2; ++ks) {
      f16x8 bk = *(const f16x8*)&Kl[(t * 16 + fr) * 64 + (((ks * 4 + g) ^ (fr & 7)) * 8)];
      acc[t] = __builtin_amdgcn_mfma_f32_16x16x32_f16(aq[ks], bk, acc[t], 0, 0, 0);
    }
  }

  float sc[8][4];
  int pq[4];
  #pragma unroll
  for (int r = 0; r < 4; ++r) pq[r] = posl[q0 + g * 4 + r];
  #pragma unroll
  for (int t = 0; t < 8; ++t) {
    float rs = rsqs[t * 16 + fr] * 0.125f;
    int pk = posl[t * 16 + fr];
    #pragma unroll
    for (int r = 0; r < 4; ++r) {
      float v_ = acc[t][r] * rs;
      if (pq[r] == pk) v_ += -1e5f;
      sc[t][r] = v_;
    }
  }
  float lsef[4];
  #pragma unroll
  for (int r = 0; r < 4; ++r) {
    float m = sc[0][r];
    #pragma unroll
    for (int t = 1; t < 8; ++t) m = fmaxf(m, sc[t][r]);
    #pragma unroll
    for (int off = 1; off < 16; off <<= 1) m = fmaxf(m, __shfl_xor(m, off, 64));
    float s = 0.f;
    #pragma unroll
    for (int t = 0; t < 8; ++t) { float e = __expf(sc[t][r] - m); sc[t][r] = e; s += e; }
    #pragma unroll
    for (int off = 1; off < 16; off <<= 1) s += __shfl_xor(s, off, 64);
    lsef[r] = m + __logf(s);
    float f = 1.0f / s;
    #pragma unroll
    for (int t = 0; t < 8; ++t) sc[t][r] *= f;
  }

  #pragma unroll
  for (int t = 0; t < 8; ++t)
    #pragma unroll
    for (int r = 0; r < 4; ++r) {
      int q = q0 + g * 4 + r;
      Pl[q * 128 + ((t * 16 + fr) ^ ((q & 7) << 3))] = (_Float16)sc[t][r];
    }
  const int rr = c >> 6;
  if (fr == 0) {
    #pragma unroll
    for (int r = 0; r < 4; ++r) {
      int q = q0 + g * 4 + r;
      logits[((size_t)n * 2 + rr) * L_SEQ + posl[q]] = lsef[r];
    }
  }

  f32x4 acc2[4];
  #pragma unroll
  for (int td = 0; td < 4; ++td) acc2[td] = (f32x4){0.f, 0.f, 0.f, 0.f};
  #pragma unroll
  for (int s = 0; s < 4; ++s) {
    f16x8 ap = *(const f16x8*)&Pl[(q0 + fr) * 128 + (((s * 4 + g) ^ (fr & 7)) * 8)];
    #pragma unroll
    for (int td = 0; td < 4; ++td) {
      f16x8 bv = *(const f16x8*)&Vt[(td * 16 + fr) * 128 + (((s * 4 + g) ^ (fr & 7)) * 8)];
      acc2[td] = __builtin_amdgcn_mfma_f32_16x16x32_f16(ap, bv, acc2[td], 0, 0, 0);
    }
  }
  #pragma unroll
  for (int r = 0; r < 4; ++r) {
    int q = q0 + g * 4 + r;
    size_t base = (((size_t)n * 2 + rr) * L_SEQ + posl[q]) * 64;
    #pragma unroll
    for (int td = 0; td < 4; ++td)
      o[base + td * 16 + fr] = (_Float16)acc2[td][r];
  }
}

// ---------------- combine hash rounds -> f16 att [8192][1024] ----------------
__global__ __launch_bounds__(256)
void lsh_combine(const __half* __restrict__ o, const float* __restrict__ logits,
                 _Float16* __restrict__ attf) {
  size_t gid = (size_t)blockIdx.x * 256 + threadIdx.x;
  int q4 = (int)(gid & 15);
  size_t nl = gid >> 4;
  int n = (int)(nl >> 12), l = (int)(nl & 4095);
  float l0 = logits[((size_t)n * 2 + 0) * L_SEQ + l];
  float l1 = logits[((size_t)n * 2 + 1) * L_SEQ + l];
  float m = fmaxf(l0, l1);
  float e0 = __expf(l0 - m), e1 = __expf(l1 - m);
  float inv = 1.0f / (e0 + e1);
  float w0 = e0 * inv, w1 = e1 * inv;
  const __half2* r0 = (const __half2*)(o + (((size_t)n * 2 + 0) * L_SEQ + l) * 64) + q4 * 2;
  const __half2* r1 = (const __half2*)(o + (((size_t)n * 2 + 1) * L_SEQ + l) * 64) + q4 * 2;
  float2 a0 = __half22float2(r0[0]), a1 = __half22float2(r0[1]);
  float2 b0 = __half22float2(r1[0]), b1 = __half22float2(r1[1]);
  f16x4 res;
  res[0] = (_Float16)(w0 * a0.x + w1 * b0.x);
  res[1] = (_Float16)(w0 * a0.y + w1 * b0.y);
  res[2] = (_Float16)(w0 * a1.x + w1 * b1.x);
  res[3] = (_Float16)(w0 * a1.y + w1 * b1.y);
  int bb = n >> 4, h = n & 15;
  *(f16x4*)(attf + ((size_t)bb * L_SEQ + l) * 1024 + h * 64 + q4 * 4) = res;
}

extern "C" void kernel_launch(void* const* d_in, const int* in_sizes, int n_in,
                              void* d_out, int out_size, void* d_ws, size_t ws_size,
                              hipStream_t stream) {
  const float* x   = (const float*)d_in[0];
  const float* Wqk = (const float*)d_in[2];
  const float* Wv  = (const float*)d_in[3];
  const float* Wo  = (const float*)d_in[4];
  const float* rot = (const float*)d_in[5];
  float* out = (float*)d_out;
  char* ws = (char*)d_ws;

  _Float16*     qkh    = (_Float16*)(ws + 0);                 // 16 MB
  _Float16*     vh     = (_Float16*)(ws + 16777216ull);       // 16 MB
  _Float16*     xh     = (_Float16*)(ws + 33554432ull);       // 16 MB (dead after gemms)
  _Float16*     attf   = (_Float16*)(ws + 33554432ull);       // overlays xh
  _Float16*     o      = (_Float16*)(ws + 50331648ull);       // 32 MB (attn output)
  // pre-attn fixup scratch overlaying the o region:
  unsigned int* lists  = (unsigned int*)(ws + 50331648ull);   // 96 KB (16 x 1536)
  unsigned int* cntp   = (unsigned int*)(ws + 50429952ull);   // 64 B
  float*        qkfixp = (float*)(ws + 50528256ull);          // 24 MB (4 K-chunks)
  float*        logits = (float*)(ws + 83886080ull);          // 1 MB
  unsigned int* st     = (unsigned int*)(ws + 84934656ull);   // 1 MB
  unsigned char* bucket = (unsigned char*)(ws + 85983232ull); // 256 KB
  _Float16*     WqkT   = (_Float16*)(ws + 86245376ull);       // 2 MB
  _Float16*     WvT    = (_Float16*)(ws + 88342528ull);       // 2 MB
  _Float16*     WoT    = (_Float16*)(ws + 90439680ull);       // 2 MB
  _Float16*     rotT   = (_Float16*)(ws + 92536832ull);       // 8 KB

  dim3 gb(256);
  dim3 gemmGrid(512);

  hipMemsetAsync(cntp, 0, 16 * sizeof(unsigned int), stream);
  cvt_f16<<<dim3(8192), gb, 0, stream>>>(x, xh);
  cvt_tr_f16<<<dim3(32, 32), gb, 0, stream>>>(Wqk, WqkT);
  cvt_tr_f16<<<dim3(32, 32), gb, 0, stream>>>(Wv, WvT);
  cvt_tr_f16<<<dim3(32, 32), gb, 0, stream>>>(Wo, WoT);
  cvt_rotT<<<dim3(1), gb, 0, stream>>>(rot, rotT);

  gemm_f16<1><<<gemmGrid, gb, 0, stream>>>(xh, WqkT, (float*)qkh, 8192, 1024, 1024);
  gemm_f16<1><<<gemmGrid, gb, 0, stream>>>(xh, WvT, (float*)vh, 8192, 1024, 1024);

  lsh_hash3<<<dim3(512), gb, 0, stream>>>(qkh, rotT, bucket, lists, cntp);
  lsh_fix_gemm<<<dim3(16, 24, 4), gb, 0, stream>>>(x, Wqk, lists, cntp, qkfixp);
  lsh_fix_rot<<<dim3(256), gb, 0, stream>>>(qkfixp, rot, lists, cntp, bucket);
  lsh_sort<<<dim3(64), gb, 0, stream>>>(bucket, st);
  lsh_attn_mfma<<<dim3(128, 32), gb, 0, stream>>>(qkh, vh, st, o, logits);
  lsh_combine<<<dim3(8192), gb, 0, stream>>>((const __half*)o, logits, attf);

  gemm_f16<0><<<gemmGrid, gb, 0, stream>>>(attf, WoT, out, 8192, 1024, 1024);
}

// Round 16
// 230.723 us; speedup vs baseline: 1.0348x; 1.0348x over previous
//
#include <hip/hip_runtime.h>
#include <hip/hip_fp16.h>

#define L_SEQ 4096
#define THR_GAP 0.08f
#define FIX_CAP 1536

typedef _Float16 f16x8 __attribute__((ext_vector_type(8)));
typedef _Float16 f16x4 __attribute__((ext_vector_type(4)));
typedef float f32x4 __attribute__((ext_vector_type(4)));

typedef __attribute__((address_space(3))) void lds_void;
typedef __attribute__((address_space(1))) void glob_void;
__device__ __forceinline__ void gload16(const _Float16* g, _Float16* l) {
  __builtin_amdgcn_global_load_lds((const glob_void*)g, (lds_void*)l, 16, 0, 0);
}

// ---------------- converts ----------------
__global__ __launch_bounds__(256)
void cvt_f16(const float* __restrict__ in, _Float16* __restrict__ out_) {
  int i = blockIdx.x * 256 + threadIdx.x;
  float4 v = ((const float4*)in)[i];
  f16x4 h;
  h[0] = (_Float16)v.x; h[1] = (_Float16)v.y;
  h[2] = (_Float16)v.z; h[3] = (_Float16)v.w;
  *(f16x4*)(out_ + (size_t)i * 4) = h;
}

__global__ __launch_bounds__(256)
void cvt_tr_f16(const float* __restrict__ W, _Float16* __restrict__ WT) {
  __shared__ _Float16 tile[32][33];
  const int bx = blockIdx.x * 32, by = blockIdx.y * 32;
  const int tx = threadIdx.x & 31, ty = threadIdx.x >> 5;
  #pragma unroll
  for (int i = ty; i < 32; i += 8)
    tile[i][tx] = (_Float16)W[(size_t)(by + i) * 1024 + bx + tx];
  __syncthreads();
  #pragma unroll
  for (int i = ty; i < 32; i += 8)
    WT[(size_t)(bx + i) * 1024 + by + tx] = tile[tx][i];
}

// rotT_f16[c][d] = rot[d][c],  c = nh*32+rb, 64x64
__global__ __launch_bounds__(256)
void cvt_rotT(const float* __restrict__ rot, _Float16* __restrict__ rotT) {
  const int tid = threadIdx.x;
  const int c = tid >> 2, d0 = (tid & 3) * 16;
  #pragma unroll
  for (int k = 0; k < 16; ++k)
    rotT[c * 64 + d0 + k] = (_Float16)rot[(d0 + k) * 64 + c];
}

// ---------------- f16 MFMA GEMM, dbuf + counted vmcnt: C = A * BT^T ----------------
// MODE 0: C row-major f32; MODE 1: scatter f16 to [n][l][d]
template<int MODE>
__global__ __launch_bounds__(256)
void gemm_f16(const _Float16* __restrict__ A, const _Float16* __restrict__ BT,
              float* __restrict__ C, int M, int K, int Nn) {
  __shared__ _Float16 As[2][128 * 64];
  __shared__ _Float16 Bs[2][128 * 64];
  const int tid = threadIdx.x;
  const int lane = tid & 63, wid = tid >> 6;
  const int wr = wid >> 1, wc = wid & 1;
  const int f = blockIdx.x;
  const int u = (f & 7) * 64 + (f >> 3);
  const int row0 = (u >> 3) * 128, col0 = (u & 7) * 128;

  f32x4 acc[4][4];
  #pragma unroll
  for (int i = 0; i < 4; ++i)
    #pragma unroll
    for (int j = 0; j < 4; ++j)
      acc[i][j] = (f32x4){0.f, 0.f, 0.f, 0.f};

  const int srow = (lane >> 3);
  const int scol = ((lane & 7) ^ srow) * 8;
  const _Float16* ga = A + (size_t)(row0 + wid * 32 + srow) * K + scol;
  const _Float16* gb = BT + (size_t)(col0 + wid * 32 + srow) * K + scol;
  const int lbase = (wid * 32) * 64;
  const int fr = lane & 15, g = lane >> 4;

#define STAGE_F16(buf, k0) do {                                          \
    _Pragma("unroll")                                                    \
    for (int i_ = 0; i_ < 4; ++i_) {                                     \
      gload16(ga + (k0) + (size_t)i_ * 8 * K, &As[buf][lbase + i_ * 8 * 64]); \
      gload16(gb + (k0) + (size_t)i_ * 8 * K, &Bs[buf][lbase + i_ * 8 * 64]); \
    }                                                                    \
  } while (0)

  STAGE_F16(0, 0);

  const int NT = K / 64;
  for (int t = 0; t < NT; ++t) {
    const int cur = t & 1, nxt = cur ^ 1;
    if (t + 1 < NT) {
      STAGE_F16(nxt, (size_t)(t + 1) * 64);
      asm volatile("s_waitcnt vmcnt(8)" ::: "memory");
    } else {
      asm volatile("s_waitcnt vmcnt(0)" ::: "memory");
    }
    __builtin_amdgcn_s_barrier();
    __builtin_amdgcn_sched_barrier(0);

    f16x8 af[4][2], bf[4][2];
    #pragma unroll
    for (int fi = 0; fi < 4; ++fi) {
      const int ra = (wr * 64 + fi * 16 + fr) * 64;
      const int rb = (wc * 64 + fi * 16 + fr) * 64;
      #pragma unroll
      for (int ks = 0; ks < 2; ++ks) {
        const int ko = (ks * 32 + g * 8) ^ ((fr & 7) * 8);
        af[fi][ks] = *(const f16x8*)(&As[cur][ra + ko]);
        bf[fi][ks] = *(const f16x8*)(&Bs[cur][rb + ko]);
      }
    }
    #pragma unroll
    for (int ks = 0; ks < 2; ++ks)
      #pragma unroll
      for (int fi = 0; fi < 4; ++fi)
        #pragma unroll
        for (int fj = 0; fj < 4; ++fj)
          acc[fi][fj] = __builtin_amdgcn_mfma_f32_16x16x32_f16(
              af[fi][ks], bf[fj][ks], acc[fi][fj], 0, 0, 0);
    __builtin_amdgcn_s_barrier();
    __builtin_amdgcn_sched_barrier(0);
  }
#undef STAGE_F16

  _Float16* Ch = (_Float16*)C;
  #pragma unroll
  for (int fi = 0; fi < 4; ++fi) {
    #pragma unroll
    for (int fj = 0; fj < 4; ++fj) {
      const int col = col0 + wc * 64 + fj * 16 + fr;
      #pragma unroll
      for (int r = 0; r < 4; ++r) {
        const int row = row0 + wr * 64 + fi * 16 + g * 4 + r;
        if (MODE == 0) {
          C[(size_t)row * Nn + col] = acc[fi][fj][r];
        } else {
          int b = row >> 12, l = row & 4095;
          int h = col >> 6, d = col & 63;
          Ch[(((size_t)(b * 16 + h) * L_SEQ) + l) * 64 + d] = (_Float16)acc[fi][fj][r];
        }
      }
    }
  }
}

// ---------------- MFMA LSH hashing + lane-local top-2 argmax ----------------
// block = 4 waves; wave handles 64 consecutive tokens of batch n.
__global__ __launch_bounds__(256, 2)
void lsh_hash3(const _Float16* __restrict__ qkh, const _Float16* __restrict__ rotT,
               unsigned char* __restrict__ bucket,
               unsigned int* __restrict__ lists, unsigned int* __restrict__ cnt) {
  __shared__ float buf[4][32][67];   // wave-private transpose tile
  const int tid = threadIdx.x, lane = tid & 63, wv = tid >> 6;
  const int fr = lane & 15, g = lane >> 4;
  const int bid = blockIdx.x;               // 512
  const int n = bid >> 4;
  const int l0 = (bid & 15) * 256 + wv * 64;
  const int h = n & 15;

  // B fragments: rotT row (= rotation output column c = nh*32+rb), k = d
  f16x8 bf[4][2];
  #pragma unroll
  for (int fj = 0; fj < 4; ++fj)
    #pragma unroll
    for (int ks = 0; ks < 2; ++ks)
      bf[fj][ks] = *(const f16x8*)&rotT[(fj * 16 + fr) * 64 + ks * 32 + g * 8];

  f32x4 acc[4][4];
  #pragma unroll
  for (int i = 0; i < 4; ++i)
    #pragma unroll
    for (int j = 0; j < 4; ++j)
      acc[i][j] = (f32x4){0.f, 0.f, 0.f, 0.f};

  const _Float16* qbase = qkh + ((size_t)n * L_SEQ + l0) * 64;
  #pragma unroll
  for (int fi = 0; fi < 4; ++fi) {
    f16x8 a0 = *(const f16x8*)(qbase + (size_t)(fi * 16 + fr) * 64 + g * 8);
    f16x8 a1 = *(const f16x8*)(qbase + (size_t)(fi * 16 + fr) * 64 + 32 + g * 8);
    #pragma unroll
    for (int fj = 0; fj < 4; ++fj) {
      acc[fi][fj] = __builtin_amdgcn_mfma_f32_16x16x32_f16(a0, bf[fj][0], acc[fi][fj], 0, 0, 0);
      acc[fi][fj] = __builtin_amdgcn_mfma_f32_16x16x32_f16(a1, bf[fj][1], acc[fi][fj], 0, 0, 0);
    }
  }

#define INS(vv, ii) do {                                                  \
    float v_ = (vv); int i_ = (ii);                                       \
    if (v_ > b1v || (v_ == b1v && i_ < b1i)) { b2v = b1v; b1v = v_; b1i = i_; } \
    else b2v = fmaxf(b2v, v_);                                            \
  } while (0)

  // two fully-unrolled passes (rule #20: acc indices must be compile-time —
  // runtime p previously spilled the whole acc array to scratch, 33 MB/dispatch)
  #pragma unroll
  for (int p = 0; p < 2; ++p) {
    #pragma unroll
    for (int q = 0; q < 2; ++q) {         // fi = 2p+q -> local rows q*16+g*4+r
      #pragma unroll
      for (int fj = 0; fj < 4; ++fj)
        #pragma unroll
        for (int r = 0; r < 4; ++r)
          buf[wv][q * 16 + g * 4 + r][fj * 16 + fr] = acc[2 * p + q][fj][r];
    }
    const int tok = lane & 31, nh = lane >> 5;
    float b1v = -3.0e38f; int b1i = 0; float b2v = -3.0e38f;
    #pragma unroll 8
    for (int j = 0; j < 32; ++j) {
      float v = buf[wv][tok][nh * 32 + j];
      INS(v, j);
      INS(-v, 32 + j);
    }
    const float gap = b1v - b2v;
    const int obi = __shfl_xor(b1i, 32, 64);
    const float ogap = __shfl_xor(gap, 32, 64);
    if (nh == 0) {
      const int t = l0 + p * 32 + tok;
      bucket[((size_t)n * 2 + 0) * L_SEQ + t] = (unsigned char)b1i;
      bucket[((size_t)n * 2 + 1) * L_SEQ + t] = (unsigned char)obi;
      if (fminf(gap, ogap) < THR_GAP) {
        unsigned int pos = atomicAdd(&cnt[h], 1u);
        if (pos < FIX_CAP)
          lists[(size_t)h * FIX_CAP + pos] = ((unsigned int)n << 12) | (unsigned int)t;
      }
    }
  }
#undef INS
}

// ---------------- fixup phase A: K-split skinny GEMM partials ----------------
__global__ __launch_bounds__(256)
void lsh_fix_gemm(const float* __restrict__ x, const float* __restrict__ Wqk,
                  const unsigned int* __restrict__ lists,
                  const unsigned int* __restrict__ cnt,
                  float* __restrict__ qkfixp) {
  __shared__ float As[32][65];
  __shared__ float Bs[32][64];
  __shared__ int rowIdx[64];
  const int h = blockIdx.x;
  const int rt = blockIdx.y;
  const int ks = blockIdx.z;
  const unsigned int nfix = min(cnt[h], (unsigned int)FIX_CAP);
  if ((unsigned int)(rt * 64) >= nfix) return;
  const int tid = threadIdx.x;
  if (tid < 64) {
    unsigned int i = (unsigned int)(rt * 64 + tid);
    if (i >= nfix) i = nfix - 1;
    unsigned int ent = lists[(size_t)h * FIX_CAP + i];
    rowIdx[tid] = (int)((ent >> 12) >> 4) * 4096 + (int)(ent & 4095);
  }
  __syncthreads();
  float acc[4][4] = {{0.f}};
  const int tx = tid & 15, ty = tid >> 4;
  const int am = tid >> 2, ae = (tid & 3) * 8;
  const int be = tid >> 3, bd = (tid & 7) * 8;
  const size_t arow = (size_t)rowIdx[am] * 1024;
  const int kbeg = ks * 256, kend = kbeg + 256;

  float4 ra0, ra1, rb0, rb1;
  {
    const float* xr = x + arow + kbeg + ae;
    ra0 = *(const float4*)xr; ra1 = *(const float4*)(xr + 4);
    const float* wr = Wqk + (size_t)(kbeg + be) * 1024 + h * 64 + bd;
    rb0 = *(const float4*)wr; rb1 = *(const float4*)(wr + 4);
  }
  for (int k0 = kbeg; k0 < kend; k0 += 32) {
    As[ae + 0][am] = ra0.x; As[ae + 1][am] = ra0.y;
    As[ae + 2][am] = ra0.z; As[ae + 3][am] = ra0.w;
    As[ae + 4][am] = ra1.x; As[ae + 5][am] = ra1.y;
    As[ae + 6][am] = ra1.z; As[ae + 7][am] = ra1.w;
    *(float4*)&Bs[be][bd] = rb0;
    *(float4*)&Bs[be][bd + 4] = rb1;
    __syncthreads();
    if (k0 + 32 < kend) {
      const float* xr = x + arow + (k0 + 32) + ae;
      ra0 = *(const float4*)xr; ra1 = *(const float4*)(xr + 4);
      const float* wr = Wqk + (size_t)(k0 + 32 + be) * 1024 + h * 64 + bd;
      rb0 = *(const float4*)wr; rb1 = *(const float4*)(wr + 4);
    }
    #pragma unroll
    for (int k = 0; k < 32; ++k) {
      float a[4], b[4];
      #pragma unroll
      for (int j = 0; j < 4; ++j) a[j] = As[k][ty * 4 + j];
      #pragma unroll
      for (int j = 0; j < 4; ++j) b[j] = Bs[k][tx * 4 + j];
      #pragma unroll
      for (int i = 0; i < 4; ++i)
        #pragma unroll
        for (int j = 0; j < 4; ++j)
          acc[i][j] += a[i] * b[j];
    }
    __syncthreads();
  }
  #pragma unroll
  for (int i = 0; i < 4; ++i) {
    int m = rt * 64 + ty * 4 + i;
    float* dst = qkfixp + (((size_t)ks * 16 + h) * FIX_CAP + m) * 64 + tx * 4;
    dst[0] = acc[i][0]; dst[1] = acc[i][1];
    dst[2] = acc[i][2]; dst[3] = acc[i][3];
  }
}

// ---------------- fixup phase B: sum K-partials, rotations, exact argmax --------
__global__ __launch_bounds__(256)
void lsh_fix_rot(const float* __restrict__ qkfixp, const float* __restrict__ rot,
                 const unsigned int* __restrict__ lists,
                 const unsigned int* __restrict__ cnt,
                 unsigned char* __restrict__ bucket) {
  __shared__ float rotL[4096];
  __shared__ float qkL[4][64];
  const int h = blockIdx.x & 15;
  const int bg = blockIdx.x >> 4;
  const int tid = threadIdx.x, lane = tid & 63, wv = tid >> 6;
  for (int i = tid; i < 4096; i += 256) rotL[i] = rot[i];
  __syncthreads();
  const unsigned int nfix = min(cnt[h], (unsigned int)FIX_CAP);
  for (unsigned int i = (unsigned int)(bg * 4 + wv); i < nfix; i += 64) {
    unsigned int ent = lists[(size_t)h * FIX_CAP + i];
    const int nn = (int)(ent >> 12), ll = (int)(ent & 4095);
    float s0 = qkfixp[(((size_t)0 * 16 + h) * FIX_CAP + i) * 64 + lane];
    float s1 = qkfixp[(((size_t)1 * 16 + h) * FIX_CAP + i) * 64 + lane];
    float s2 = qkfixp[(((size_t)2 * 16 + h) * FIX_CAP + i) * 64 + lane];
    float s3 = qkfixp[(((size_t)3 * 16 + h) * FIX_CAP + i) * 64 + lane];
    qkL[wv][lane] = ((s0 + s1) + s2) + s3;
    asm volatile("s_waitcnt vmcnt(0) lgkmcnt(0)" ::: "memory");
    float v = 0.f;
    #pragma unroll 16
    for (int d = 0; d < 64; ++d)
      v += qkL[wv][d] * rotL[d * 64 + lane];
    const int r = lane & 31;
    float vneg = -v;
    float bv; int bi;
    if (vneg > v) { bv = vneg; bi = 32 + r; } else { bv = v; bi = r; }
    #pragma unroll
    for (int off = 1; off < 32; off <<= 1) {
      float ov = __shfl_xor(bv, off, 64);
      int oi = __shfl_xor(bi, off, 64);
      if (ov > bv || (ov == bv && oi < bi)) { bv = ov; bi = oi; }
    }
    if (r == 0) {
      int hr = lane >> 5;
      bucket[((size_t)(nn * 2 + hr)) * L_SEQ + ll] = (unsigned char)bi;
    }
  }
}

// ---------------- parallel stable counting sort per (n, round) ----------------
__global__ __launch_bounds__(256)
void lsh_sort(const unsigned char* __restrict__ bucket, unsigned int* __restrict__ st) {
  __shared__ unsigned short cnt[64][257];
  __shared__ unsigned int bstart[64];
  __shared__ unsigned char bkt[4096];
  const int nr = blockIdx.x;
  const int tid = threadIdx.x;
  const unsigned char* bsrc = bucket + (size_t)nr * L_SEQ;
  for (int i = tid; i < 1024; i += 256)
    ((unsigned int*)bkt)[i] = ((const unsigned int*)bsrc)[i];
  #pragma unroll
  for (int b = 0; b < 64; ++b) cnt[b][tid] = 0;
  __syncthreads();
  uint4 wv = ((const uint4*)bkt)[tid];
  unsigned int wsg[4] = {wv.x, wv.y, wv.z, wv.w};
  #pragma unroll
  for (int k = 0; k < 16; ++k) {
    int b = (wsg[k >> 2] >> ((k & 3) * 8)) & 63;
    cnt[b][tid]++;
  }
  __syncthreads();
  if (tid < 64) {
    const int b = tid;
    unsigned int run = 0;
    for (int t = 0; t < 256; ++t) {
      unsigned int c = cnt[b][t];
      cnt[b][t] = (unsigned short)run;
      run += c;
    }
    unsigned int incl = run;
    #pragma unroll
    for (int off = 1; off < 64; off <<= 1) {
      unsigned int up = (unsigned int)__shfl_up((int)incl, off);
      if (tid >= off) incl += up;
    }
    bstart[b] = incl - run;
  }
  __syncthreads();
  const int n = nr >> 1, r = nr & 1;
  unsigned int* dst = st + (size_t)n * 8192 + (size_t)r * 4096;
  #pragma unroll
  for (int k = 0; k < 16; ++k) {
    int b = (wsg[k >> 2] >> ((k & 3) * 8)) & 63;
    unsigned int idx = bstart[b] + cnt[b][tid];
    cnt[b][tid]++;
    dst[idx] = (unsigned int)(tid * 16 + k);
  }
}

// ---------------- MFMA chunked local attention (f16 qk gather) ----------------
__global__ __launch_bounds__(256)
void lsh_attn_mfma(const _Float16* __restrict__ qkh, const _Float16* __restrict__ vh,
                   const unsigned int* __restrict__ st,
                   _Float16* __restrict__ o, float* __restrict__ logits) {
  __shared__ _Float16 Kl[128 * 64];
  __shared__ _Float16 Vt[64 * 128];
  __shared__ _Float16 Pl[64 * 128];
  __shared__ float rsqs[128];
  __shared__ float partial[256];
  __shared__ int posl[128];

  const int tid = threadIdx.x;
  const int lane = tid & 63, wid = tid >> 6;
  const int fr = lane & 15, g = lane >> 4;
  const int c = blockIdx.x, n = blockIdx.y;
  const int cprev = (c + 127) & 127;

  if (tid < 128) {
    int p = (tid < 64) ? (c * 64 + tid) : (cprev * 64 + (tid - 64));
    posl[tid] = (int)st[(size_t)n * 8192 + p];
  }
  __syncthreads();

  {
    const int j = tid >> 1, h = tid & 1;
    const int gpos = posl[j];
    const f16x8* srcK = (const f16x8*)(qkh + ((size_t)n * L_SEQ + gpos) * 64 + h * 32);
    const f16x8* srcV = (const f16x8*)(vh + ((size_t)n * L_SEQ + gpos) * 64 + h * 32);
    float ss = 0.f;
    #pragma unroll
    for (int i = 0; i < 4; ++i) {
      f16x8 kv = srcK[i];
      f16x8 vv4 = srcV[i];
      #pragma unroll
      for (int e = 0; e < 8; ++e) {
        float xv = (float)kv[e];
        ss += xv * xv;
        int d = h * 32 + i * 8 + e;
        Vt[d * 128 + (j ^ ((d & 7) << 3))] = vv4[e];
      }
      int ch = h * 4 + i;
      *(f16x8*)(&Kl[j * 64 + ((ch ^ (j & 7)) * 8)]) = kv;
    }
    partial[tid] = ss;
  }
  __syncthreads();
  if (tid < 128)
    rsqs[tid] = rsqrtf(fmaxf(partial[tid * 2] + partial[tid * 2 + 1], 1e-12f));
  __syncthreads();

  const int q0 = wid * 16;
  f32x4 acc[8];
  #pragma unroll
  for (int t = 0; t < 8; ++t) acc[t] = (f32x4){0.f, 0.f, 0.f, 0.f};
  f16x8 aq[2];
  #pragma unroll
  for (int ks = 0; ks < 2; ++ks)
    aq[ks] = *(const f16x8*)&Kl[(q0 + fr) * 64 + (((ks * 4 + g) ^ (fr & 7)) * 8)];
  #pragma unroll
  for (int t = 0; t < 8; ++t) {
    #pragma unroll
    for (int ks = 0; ks < 2; ++ks) {
      f16x8 bk = *(const f16x8*)&Kl[(t * 16 + fr) * 64 + (((ks * 4 + g) ^ (fr & 7)) * 8)];
      acc[t] = __builtin_amdgcn_mfma_f32_16x16x32_f16(aq[ks], bk, acc[t], 0, 0, 0);
    }
  }

  float sc[8][4];
  int pq[4];
  #pragma unroll
  for (int r = 0; r < 4; ++r) pq[r] = posl[q0 + g * 4 + r];
  #pragma unroll
  for (int t = 0; t < 8; ++t) {
    float rs = rsqs[t * 16 + fr] * 0.125f;
    int pk = posl[t * 16 + fr];
    #pragma unroll
    for (int r = 0; r < 4; ++r) {
      float v_ = acc[t][r] * rs;
      if (pq[r] == pk) v_ += -1e5f;
      sc[t][r] = v_;
    }
  }
  float lsef[4];
  #pragma unroll
  for (int r = 0; r < 4; ++r) {
    float m = sc[0][r];
    #pragma unroll
    for (int t = 1; t < 8; ++t) m = fmaxf(m, sc[t][r]);
    #pragma unroll
    for (int off = 1; off < 16; off <<= 1) m = fmaxf(m, __shfl_xor(m, off, 64));
    float s = 0.f;
    #pragma unroll
    for (int t = 0; t < 8; ++t) { float e = __expf(sc[t][r] - m); sc[t][r] = e; s += e; }
    #pragma unroll
    for (int off = 1; off < 16; off <<= 1) s += __shfl_xor(s, off, 64);
    lsef[r] = m + __logf(s);
    float f = 1.0f / s;
    #pragma unroll
    for (int t = 0; t < 8; ++t) sc[t][r] *= f;
  }

  #pragma unroll
  for (int t = 0; t < 8; ++t)
    #pragma unroll
    for (int r = 0; r < 4; ++r) {
      int q = q0 + g * 4 + r;
      Pl[q * 128 + ((t * 16 + fr) ^ ((q & 7) << 3))] = (_Float16)sc[t][r];
    }
  const int rr = c >> 6;
  if (fr == 0) {
    #pragma unroll
    for (int r = 0; r < 4; ++r) {
      int q = q0 + g * 4 + r;
      logits[((size_t)n * 2 + rr) * L_SEQ + posl[q]] = lsef[r];
    }
  }

  f32x4 acc2[4];
  #pragma unroll
  for (int td = 0; td < 4; ++td) acc2[td] = (f32x4){0.f, 0.f, 0.f, 0.f};
  #pragma unroll
  for (int s = 0; s < 4; ++s) {
    f16x8 ap = *(const f16x8*)&Pl[(q0 + fr) * 128 + (((s * 4 + g) ^ (fr & 7)) * 8)];
    #pragma unroll
    for (int td = 0; td < 4; ++td) {
      f16x8 bv = *(const f16x8*)&Vt[(td * 16 + fr) * 128 + (((s * 4 + g) ^ (fr & 7)) * 8)];
      acc2[td] = __builtin_amdgcn_mfma_f32_16x16x32_f16(ap, bv, acc2[td], 0, 0, 0);
    }
  }
  #pragma unroll
  for (int r = 0; r < 4; ++r) {
    int q = q0 + g * 4 + r;
    size_t base = (((size_t)n * 2 + rr) * L_SEQ + posl[q]) * 64;
    #pragma unroll
    for (int td = 0; td < 4; ++td)
      o[base + td * 16 + fr] = (_Float16)acc2[td][r];
  }
}

// ---------------- combine hash rounds -> f16 att [8192][1024] ----------------
__global__ __launch_bounds__(256)
void lsh_combine(const __half* __restrict__ o, const float* __restrict__ logits,
                 _Float16* __restrict__ attf) {
  size_t gid = (size_t)blockIdx.x * 256 + threadIdx.x;
  int q4 = (int)(gid & 15);
  size_t nl = gid >> 4;
  int n = (int)(nl >> 12), l = (int)(nl & 4095);
  float l0 = logits[((size_t)n * 2 + 0) * L_SEQ + l];
  float l1 = logits[((size_t)n * 2 + 1) * L_SEQ + l];
  float m = fmaxf(l0, l1);
  float e0 = __expf(l0 - m), e1 = __expf(l1 - m);
  float inv = 1.0f / (e0 + e1);
  float w0 = e0 * inv, w1 = e1 * inv;
  const __half2* r0 = (const __half2*)(o + (((size_t)n * 2 + 0) * L_SEQ + l) * 64) + q4 * 2;
  const __half2* r1 = (const __half2*)(o + (((size_t)n * 2 + 1) * L_SEQ + l) * 64) + q4 * 2;
  float2 a0 = __half22float2(r0[0]), a1 = __half22float2(r0[1]);
  float2 b0 = __half22float2(r1[0]), b1 = __half22float2(r1[1]);
  f16x4 res;
  res[0] = (_Float16)(w0 * a0.x + w1 * b0.x);
  res[1] = (_Float16)(w0 * a0.y + w1 * b0.y);
  res[2] = (_Float16)(w0 * a1.x + w1 * b1.x);
  res[3] = (_Float16)(w0 * a1.y + w1 * b1.y);
  int bb = n >> 4, h = n & 15;
  *(f16x4*)(attf + ((size_t)bb * L_SEQ + l) * 1024 + h * 64 + q4 * 4) = res;
}

extern "C" void kernel_launch(void* const* d_in, const int* in_sizes, int n_in,
                              void* d_out, int out_size, void* d_ws, size_t ws_size,
                              hipStream_t stream) {
  const float* x   = (const float*)d_in[0];
  const float* Wqk = (const float*)d_in[2];
  const float* Wv  = (const float*)d_in[3];
  const float* Wo  = (const float*)d_in[4];
  const float* rot = (const float*)d_in[5];
  float* out = (float*)d_out;
  char* ws = (char*)d_ws;

  _Float16*     qkh    = (_Float16*)(ws + 0);                 // 16 MB
  _Float16*     vh     = (_Float16*)(ws + 16777216ull);       // 16 MB
  _Float16*     xh     = (_Float16*)(ws + 33554432ull);       // 16 MB (dead after gemms)
  _Float16*     attf   = (_Float16*)(ws + 33554432ull);       // overlays xh
  _Float16*     o      = (_Float16*)(ws + 50331648ull);       // 32 MB (attn output)
  // pre-attn fixup scratch overlaying the o region:
  unsigned int* lists  = (unsigned int*)(ws + 50331648ull);   // 96 KB (16 x 1536)
  unsigned int* cntp   = (unsigned int*)(ws + 50429952ull);   // 64 B
  float*        qkfixp = (float*)(ws + 50528256ull);          // 24 MB (4 K-chunks)
  float*        logits = (float*)(ws + 83886080ull);          // 1 MB
  unsigned int* st     = (unsigned int*)(ws + 84934656ull);   // 1 MB
  unsigned char* bucket = (unsigned char*)(ws + 85983232ull); // 256 KB
  _Float16*     WqkT   = (_Float16*)(ws + 86245376ull);       // 2 MB
  _Float16*     WvT    = (_Float16*)(ws + 88342528ull);       // 2 MB
  _Float16*     WoT    = (_Float16*)(ws + 90439680ull);       // 2 MB
  _Float16*     rotT   = (_Float16*)(ws + 92536832ull);       // 8 KB

  dim3 gb(256);
  dim3 gemmGrid(512);

  hipMemsetAsync(cntp, 0, 16 * sizeof(unsigned int), stream);
  cvt_f16<<<dim3(8192), gb, 0, stream>>>(x, xh);
  cvt_tr_f16<<<dim3(32, 32), gb, 0, stream>>>(Wqk, WqkT);
  cvt_tr_f16<<<dim3(32, 32), gb, 0, stream>>>(Wv, WvT);
  cvt_tr_f16<<<dim3(32, 32), gb, 0, stream>>>(Wo, WoT);
  cvt_rotT<<<dim3(1), gb, 0, stream>>>(rot, rotT);

  gemm_f16<1><<<gemmGrid, gb, 0, stream>>>(xh, WqkT, (float*)qkh, 8192, 1024, 1024);
  gemm_f16<1><<<gemmGrid, gb, 0, stream>>>(xh, WvT, (float*)vh, 8192, 1024, 1024);

  lsh_hash3<<<dim3(512), gb, 0, stream>>>(qkh, rotT, bucket, lists, cntp);
  lsh_fix_gemm<<<dim3(16, 24, 4), gb, 0, stream>>>(x, Wqk, lists, cntp, qkfixp);
  lsh_fix_rot<<<dim3(256), gb, 0, stream>>>(qkfixp, rot, lists, cntp, bucket);
  lsh_sort<<<dim3(64), gb, 0, stream>>>(bucket, st);
  lsh_attn_mfma<<<dim3(128, 32), gb, 0, stream>>>(qkh, vh, st, o, logits);
  lsh_combine<<<dim3(8192), gb, 0, stream>>>((const __half*)o, logits, attf);

  gemm_f16<0><<<gemmGrid, gb, 0, stream>>>(attf, WoT, out, 8192, 1024, 1024);
}

// Round 17
// 228.884 us; speedup vs baseline: 1.0431x; 1.0080x over previous
//
#include <hip/hip_runtime.h>
#include <hip/hip_fp16.h>

#define L_SEQ 4096
#define THR_GAP 0.08f
#define FIX_CAP 1536

typedef _Float16 f16x8 __attribute__((ext_vector_type(8)));
typedef _Float16 f16x4 __attribute__((ext_vector_type(4)));
typedef float f32x4 __attribute__((ext_vector_type(4)));

typedef __attribute__((address_space(3))) void lds_void;
typedef __attribute__((address_space(1))) void glob_void;
__device__ __forceinline__ void gload16(const _Float16* g, _Float16* l) {
  __builtin_amdgcn_global_load_lds((const glob_void*)g, (lds_void*)l, 16, 0, 0);
}

// ---------------- converts ----------------
__global__ __launch_bounds__(256)
void cvt_f16(const float* __restrict__ in, _Float16* __restrict__ out_) {
  int i = blockIdx.x * 256 + threadIdx.x;
  float4 v = ((const float4*)in)[i];
  f16x4 h;
  h[0] = (_Float16)v.x; h[1] = (_Float16)v.y;
  h[2] = (_Float16)v.z; h[3] = (_Float16)v.w;
  *(f16x4*)(out_ + (size_t)i * 4) = h;
}

__global__ __launch_bounds__(256)
void cvt_tr_f16(const float* __restrict__ W, _Float16* __restrict__ WT) {
  __shared__ _Float16 tile[32][33];
  const int bx = blockIdx.x * 32, by = blockIdx.y * 32;
  const int tx = threadIdx.x & 31, ty = threadIdx.x >> 5;
  #pragma unroll
  for (int i = ty; i < 32; i += 8)
    tile[i][tx] = (_Float16)W[(size_t)(by + i) * 1024 + bx + tx];
  __syncthreads();
  #pragma unroll
  for (int i = ty; i < 32; i += 8)
    WT[(size_t)(bx + i) * 1024 + by + tx] = tile[tx][i];
}

// rotT_f16[c][d] = rot[d][c],  c = nh*32+rb, 64x64
__global__ __launch_bounds__(256)
void cvt_rotT(const float* __restrict__ rot, _Float16* __restrict__ rotT) {
  const int tid = threadIdx.x;
  const int c = tid >> 2, d0 = (tid & 3) * 16;
  #pragma unroll
  for (int k = 0; k < 16; ++k)
    rotT[c * 64 + d0 + k] = (_Float16)rot[(d0 + k) * 64 + c];
}

// ---------------- f16 MFMA GEMM, dbuf + counted vmcnt: C = A * BT^T ----------------
// MODE 0: C row-major f32; MODE 1: scatter f16 to [n][l][d]
template<int MODE>
__global__ __launch_bounds__(256)
void gemm_f16(const _Float16* __restrict__ A, const _Float16* __restrict__ BT,
              float* __restrict__ C, int M, int K, int Nn) {
  __shared__ _Float16 As[2][128 * 64];
  __shared__ _Float16 Bs[2][128 * 64];
  const int tid = threadIdx.x;
  const int lane = tid & 63, wid = tid >> 6;
  const int wr = wid >> 1, wc = wid & 1;
  const int f = blockIdx.x;
  const int u = (f & 7) * 64 + (f >> 3);
  const int row0 = (u >> 3) * 128, col0 = (u & 7) * 128;

  f32x4 acc[4][4];
  #pragma unroll
  for (int i = 0; i < 4; ++i)
    #pragma unroll
    for (int j = 0; j < 4; ++j)
      acc[i][j] = (f32x4){0.f, 0.f, 0.f, 0.f};

  const int srow = (lane >> 3);
  const int scol = ((lane & 7) ^ srow) * 8;
  const _Float16* ga = A + (size_t)(row0 + wid * 32 + srow) * K + scol;
  const _Float16* gb = BT + (size_t)(col0 + wid * 32 + srow) * K + scol;
  const int lbase = (wid * 32) * 64;
  const int fr = lane & 15, g = lane >> 4;

#define STAGE_F16(buf, k0) do {                                          \
    _Pragma("unroll")                                                    \
    for (int i_ = 0; i_ < 4; ++i_) {                                     \
      gload16(ga + (k0) + (size_t)i_ * 8 * K, &As[buf][lbase + i_ * 8 * 64]); \
      gload16(gb + (k0) + (size_t)i_ * 8 * K, &Bs[buf][lbase + i_ * 8 * 64]); \
    }                                                                    \
  } while (0)

  STAGE_F16(0, 0);

  const int NT = K / 64;
  for (int t = 0; t < NT; ++t) {
    const int cur = t & 1, nxt = cur ^ 1;
    if (t + 1 < NT) {
      STAGE_F16(nxt, (size_t)(t + 1) * 64);
      asm volatile("s_waitcnt vmcnt(8)" ::: "memory");
    } else {
      asm volatile("s_waitcnt vmcnt(0)" ::: "memory");
    }
    __builtin_amdgcn_s_barrier();
    __builtin_amdgcn_sched_barrier(0);

    f16x8 af[4][2], bf[4][2];
    #pragma unroll
    for (int fi = 0; fi < 4; ++fi) {
      const int ra = (wr * 64 + fi * 16 + fr) * 64;
      const int rb = (wc * 64 + fi * 16 + fr) * 64;
      #pragma unroll
      for (int ks = 0; ks < 2; ++ks) {
        const int ko = (ks * 32 + g * 8) ^ ((fr & 7) * 8);
        af[fi][ks] = *(const f16x8*)(&As[cur][ra + ko]);
        bf[fi][ks] = *(const f16x8*)(&Bs[cur][rb + ko]);
      }
    }
    #pragma unroll
    for (int ks = 0; ks < 2; ++ks)
      #pragma unroll
      for (int fi = 0; fi < 4; ++fi)
        #pragma unroll
        for (int fj = 0; fj < 4; ++fj)
          acc[fi][fj] = __builtin_amdgcn_mfma_f32_16x16x32_f16(
              af[fi][ks], bf[fj][ks], acc[fi][fj], 0, 0, 0);
    __builtin_amdgcn_s_barrier();
    __builtin_amdgcn_sched_barrier(0);
  }
#undef STAGE_F16

  _Float16* Ch = (_Float16*)C;
  #pragma unroll
  for (int fi = 0; fi < 4; ++fi) {
    #pragma unroll
    for (int fj = 0; fj < 4; ++fj) {
      const int col = col0 + wc * 64 + fj * 16 + fr;
      #pragma unroll
      for (int r = 0; r < 4; ++r) {
        const int row = row0 + wr * 64 + fi * 16 + g * 4 + r;
        if (MODE == 0) {
          C[(size_t)row * Nn + col] = acc[fi][fj][r];
        } else {
          int b = row >> 12, l = row & 4095;
          int h = col >> 6, d = col & 63;
          Ch[(((size_t)(b * 16 + h) * L_SEQ) + l) * 64 + d] = (_Float16)acc[fi][fj][r];
        }
      }
    }
  }
}

// ---------------- MFMA LSH hashing + branchless tree top-2 ----------------
// block = 4 waves; wave handles 32 consecutive tokens of batch n.
__global__ __launch_bounds__(256, 2)
void lsh_hash3(const _Float16* __restrict__ qkh, const _Float16* __restrict__ rotT,
               unsigned char* __restrict__ bucket,
               unsigned int* __restrict__ lists, unsigned int* __restrict__ cnt) {
  __shared__ float buf[4][32][65];   // wave-private transpose tile [token][rot-col]
  const int tid = threadIdx.x, lane = tid & 63, wv = tid >> 6;
  const int fr = lane & 15, g = lane >> 4;
  const int bid = blockIdx.x;               // 1024
  const int n = bid >> 5;
  const int l0 = (bid & 31) * 128 + wv * 32;
  const int h = n & 15;

  // B fragments: rotT row (= rotation output column c = nh*32+rb), k = d
  f16x8 bf[4][2];
  #pragma unroll
  for (int fj = 0; fj < 4; ++fj)
    #pragma unroll
    for (int ks = 0; ks < 2; ++ks)
      bf[fj][ks] = *(const f16x8*)&rotT[(fj * 16 + fr) * 64 + ks * 32 + g * 8];

  f32x4 acc[2][4];
  #pragma unroll
  for (int i = 0; i < 2; ++i)
    #pragma unroll
    for (int j = 0; j < 4; ++j)
      acc[i][j] = (f32x4){0.f, 0.f, 0.f, 0.f};

  const _Float16* qbase = qkh + ((size_t)n * L_SEQ + l0) * 64;
  #pragma unroll
  for (int fi = 0; fi < 2; ++fi) {
    f16x8 a0 = *(const f16x8*)(qbase + (size_t)(fi * 16 + fr) * 64 + g * 8);
    f16x8 a1 = *(const f16x8*)(qbase + (size_t)(fi * 16 + fr) * 64 + 32 + g * 8);
    #pragma unroll
    for (int fj = 0; fj < 4; ++fj) {
      acc[fi][fj] = __builtin_amdgcn_mfma_f32_16x16x32_f16(a0, bf[fj][0], acc[fi][fj], 0, 0, 0);
      acc[fi][fj] = __builtin_amdgcn_mfma_f32_16x16x32_f16(a1, bf[fj][1], acc[fi][fj], 0, 0, 0);
    }
  }

  // transpose to LDS: row = token-in-wave (0..31), col = rotation output (0..63)
  #pragma unroll
  for (int fi = 0; fi < 2; ++fi)
    #pragma unroll
    for (int fj = 0; fj < 4; ++fj)
      #pragma unroll
      for (int r = 0; r < 4; ++r)
        buf[wv][fi * 16 + g * 4 + r][fj * 16 + fr] = acc[fi][fj][r];

  // lane = (token, round); branchless tree top-2 over [v, -v]
  const int tok = lane & 31, nh = lane >> 5;
  float v[32];
  #pragma unroll
  for (int j = 0; j < 32; ++j) v[j] = buf[wv][tok][nh * 32 + j];
  float maxv = v[0], minv = v[0];
  #pragma unroll
  for (int j = 1; j < 32; ++j) { maxv = fmaxf(maxv, v[j]); minv = fminf(minv, v[j]); }
  float m1 = fmaxf(maxv, -minv);
  int idx = 64;
  #pragma unroll
  for (int j = 0; j < 32; ++j) idx = min(idx, (v[j] == m1) ? j : 64);
  #pragma unroll
  for (int j = 0; j < 32; ++j) idx = min(idx, (-v[j] == m1) ? 32 + j : 64);
  float m2 = -3.0e38f;
  #pragma unroll
  for (int j = 0; j < 32; ++j) m2 = fmaxf(m2, (j == idx) ? -3.0e38f : v[j]);
  #pragma unroll
  for (int j = 0; j < 32; ++j) m2 = fmaxf(m2, ((32 + j) == idx) ? -3.0e38f : -v[j]);
  const float gap = m1 - m2;
  const int obi = __shfl_xor(idx, 32, 64);
  const float ogap = __shfl_xor(gap, 32, 64);
  if (nh == 0) {
    const int t = l0 + tok;
    bucket[((size_t)n * 2 + 0) * L_SEQ + t] = (unsigned char)idx;
    bucket[((size_t)n * 2 + 1) * L_SEQ + t] = (unsigned char)obi;
    if (fminf(gap, ogap) < THR_GAP) {
      unsigned int pos = atomicAdd(&cnt[h], 1u);
      if (pos < FIX_CAP)
        lists[(size_t)h * FIX_CAP + pos] = ((unsigned int)n << 12) | (unsigned int)t;
    }
  }
}

// ---------------- fixup phase A: K-split skinny GEMM partials ----------------
__global__ __launch_bounds__(256)
void lsh_fix_gemm(const float* __restrict__ x, const float* __restrict__ Wqk,
                  const unsigned int* __restrict__ lists,
                  const unsigned int* __restrict__ cnt,
                  float* __restrict__ qkfixp) {
  __shared__ float As[32][65];
  __shared__ float Bs[32][64];
  __shared__ int rowIdx[64];
  const int h = blockIdx.x;
  const int rt = blockIdx.y;
  const int ks = blockIdx.z;
  const unsigned int nfix = min(cnt[h], (unsigned int)FIX_CAP);
  if ((unsigned int)(rt * 64) >= nfix) return;
  const int tid = threadIdx.x;
  if (tid < 64) {
    unsigned int i = (unsigned int)(rt * 64 + tid);
    if (i >= nfix) i = nfix - 1;
    unsigned int ent = lists[(size_t)h * FIX_CAP + i];
    rowIdx[tid] = (int)((ent >> 12) >> 4) * 4096 + (int)(ent & 4095);
  }
  __syncthreads();
  float acc[4][4] = {{0.f}};
  const int tx = tid & 15, ty = tid >> 4;
  const int am = tid >> 2, ae = (tid & 3) * 8;
  const int be = tid >> 3, bd = (tid & 7) * 8;
  const size_t arow = (size_t)rowIdx[am] * 1024;
  const int kbeg = ks * 256, kend = kbeg + 256;

  float4 ra0, ra1, rb0, rb1;
  {
    const float* xr = x + arow + kbeg + ae;
    ra0 = *(const float4*)xr; ra1 = *(const float4*)(xr + 4);
    const float* wr = Wqk + (size_t)(kbeg + be) * 1024 + h * 64 + bd;
    rb0 = *(const float4*)wr; rb1 = *(const float4*)(wr + 4);
  }
  for (int k0 = kbeg; k0 < kend; k0 += 32) {
    As[ae + 0][am] = ra0.x; As[ae + 1][am] = ra0.y;
    As[ae + 2][am] = ra0.z; As[ae + 3][am] = ra0.w;
    As[ae + 4][am] = ra1.x; As[ae + 5][am] = ra1.y;
    As[ae + 6][am] = ra1.z; As[ae + 7][am] = ra1.w;
    *(float4*)&Bs[be][bd] = rb0;
    *(float4*)&Bs[be][bd + 4] = rb1;
    __syncthreads();
    if (k0 + 32 < kend) {
      const float* xr = x + arow + (k0 + 32) + ae;
      ra0 = *(const float4*)xr; ra1 = *(const float4*)(xr + 4);
      const float* wr = Wqk + (size_t)(k0 + 32 + be) * 1024 + h * 64 + bd;
      rb0 = *(const float4*)wr; rb1 = *(const float4*)(wr + 4);
    }
    #pragma unroll
    for (int k = 0; k < 32; ++k) {
      float a[4], b[4];
      #pragma unroll
      for (int j = 0; j < 4; ++j) a[j] = As[k][ty * 4 + j];
      #pragma unroll
      for (int j = 0; j < 4; ++j) b[j] = Bs[k][tx * 4 + j];
      #pragma unroll
      for (int i = 0; i < 4; ++i)
        #pragma unroll
        for (int j = 0; j < 4; ++j)
          acc[i][j] += a[i] * b[j];
    }
    __syncthreads();
  }
  #pragma unroll
  for (int i = 0; i < 4; ++i) {
    int m = rt * 64 + ty * 4 + i;
    float* dst = qkfixp + (((size_t)ks * 16 + h) * FIX_CAP + m) * 64 + tx * 4;
    dst[0] = acc[i][0]; dst[1] = acc[i][1];
    dst[2] = acc[i][2]; dst[3] = acc[i][3];
  }
}

// ---------------- fixup phase B: sum K-partials, rotations, exact argmax --------
__global__ __launch_bounds__(256)
void lsh_fix_rot(const float* __restrict__ qkfixp, const float* __restrict__ rot,
                 const unsigned int* __restrict__ lists,
                 const unsigned int* __restrict__ cnt,
                 unsigned char* __restrict__ bucket) {
  __shared__ float rotL[4096];
  __shared__ float qkL[4][64];
  const int h = blockIdx.x & 15;
  const int bg = blockIdx.x >> 4;
  const int tid = threadIdx.x, lane = tid & 63, wv = tid >> 6;
  for (int i = tid; i < 4096; i += 256) rotL[i] = rot[i];
  __syncthreads();
  const unsigned int nfix = min(cnt[h], (unsigned int)FIX_CAP);
  for (unsigned int i = (unsigned int)(bg * 4 + wv); i < nfix; i += 64) {
    unsigned int ent = lists[(size_t)h * FIX_CAP + i];
    const int nn = (int)(ent >> 12), ll = (int)(ent & 4095);
    float s0 = qkfixp[(((size_t)0 * 16 + h) * FIX_CAP + i) * 64 + lane];
    float s1 = qkfixp[(((size_t)1 * 16 + h) * FIX_CAP + i) * 64 + lane];
    float s2 = qkfixp[(((size_t)2 * 16 + h) * FIX_CAP + i) * 64 + lane];
    float s3 = qkfixp[(((size_t)3 * 16 + h) * FIX_CAP + i) * 64 + lane];
    qkL[wv][lane] = ((s0 + s1) + s2) + s3;
    asm volatile("s_waitcnt vmcnt(0) lgkmcnt(0)" ::: "memory");
    float v = 0.f;
    #pragma unroll 16
    for (int d = 0; d < 64; ++d)
      v += qkL[wv][d] * rotL[d * 64 + lane];
    const int r = lane & 31;
    float vneg = -v;
    float bv; int bi;
    if (vneg > v) { bv = vneg; bi = 32 + r; } else { bv = v; bi = r; }
    #pragma unroll
    for (int off = 1; off < 32; off <<= 1) {
      float ov = __shfl_xor(bv, off, 64);
      int oi = __shfl_xor(bi, off, 64);
      if (ov > bv || (ov == bv && oi < bi)) { bv = ov; bi = oi; }
    }
    if (r == 0) {
      int hr = lane >> 5;
      bucket[((size_t)(nn * 2 + hr)) * L_SEQ + ll] = (unsigned char)bi;
    }
  }
}

// ---------------- parallel stable counting sort per (n, round) ----------------
__global__ __launch_bounds__(256)
void lsh_sort(const unsigned char* __restrict__ bucket, unsigned int* __restrict__ st) {
  __shared__ unsigned short cnt[64][257];
  __shared__ unsigned int bstart[64];
  __shared__ unsigned char bkt[4096];
  const int nr = blockIdx.x;
  const int tid = threadIdx.x;
  const unsigned char* bsrc = bucket + (size_t)nr * L_SEQ;
  for (int i = tid; i < 1024; i += 256)
    ((unsigned int*)bkt)[i] = ((const unsigned int*)bsrc)[i];
  #pragma unroll
  for (int b = 0; b < 64; ++b) cnt[b][tid] = 0;
  __syncthreads();
  uint4 wv = ((const uint4*)bkt)[tid];
  unsigned int wsg[4] = {wv.x, wv.y, wv.z, wv.w};
  #pragma unroll
  for (int k = 0; k < 16; ++k) {
    int b = (wsg[k >> 2] >> ((k & 3) * 8)) & 63;
    cnt[b][tid]++;
  }
  __syncthreads();
  if (tid < 64) {
    const int b = tid;
    unsigned int run = 0;
    for (int t = 0; t < 256; ++t) {
      unsigned int c = cnt[b][t];
      cnt[b][t] = (unsigned short)run;
      run += c;
    }
    unsigned int incl = run;
    #pragma unroll
    for (int off = 1; off < 64; off <<= 1) {
      unsigned int up = (unsigned int)__shfl_up((int)incl, off);
      if (tid >= off) incl += up;
    }
    bstart[b] = incl - run;
  }
  __syncthreads();
  const int n = nr >> 1, r = nr & 1;
  unsigned int* dst = st + (size_t)n * 8192 + (size_t)r * 4096;
  #pragma unroll
  for (int k = 0; k < 16; ++k) {
    int b = (wsg[k >> 2] >> ((k & 3) * 8)) & 63;
    unsigned int idx = bstart[b] + cnt[b][tid];
    cnt[b][tid]++;
    dst[idx] = (unsigned int)(tid * 16 + k);
  }
}

// ---------------- MFMA chunked local attention (f16 qk gather) ----------------
__global__ __launch_bounds__(256)
void lsh_attn_mfma(const _Float16* __restrict__ qkh, const _Float16* __restrict__ vh,
                   const unsigned int* __restrict__ st,
                   _Float16* __restrict__ o, float* __restrict__ logits) {
  __shared__ _Float16 Kl[128 * 64];
  __shared__ _Float16 Vt[64 * 128];
  __shared__ _Float16 Pl[64 * 128];
  __shared__ float rsqs[128];
  __shared__ float partial[256];
  __shared__ int posl[128];

  const int tid = threadIdx.x;
  const int lane = tid & 63, wid = tid >> 6;
  const int fr = lane & 15, g = lane >> 4;
  const int c = blockIdx.x, n = blockIdx.y;
  const int cprev = (c + 127) & 127;

  if (tid < 128) {
    int p = (tid < 64) ? (c * 64 + tid) : (cprev * 64 + (tid - 64));
    posl[tid] = (int)st[(size_t)n * 8192 + p];
  }
  __syncthreads();

  {
    const int j = tid >> 1, h = tid & 1;
    const int gpos = posl[j];
    const f16x8* srcK = (const f16x8*)(qkh + ((size_t)n * L_SEQ + gpos) * 64 + h * 32);
    const f16x8* srcV = (const f16x8*)(vh + ((size_t)n * L_SEQ + gpos) * 64 + h * 32);
    float ss = 0.f;
    #pragma unroll
    for (int i = 0; i < 4; ++i) {
      f16x8 kv = srcK[i];
      f16x8 vv4 = srcV[i];
      #pragma unroll
      for (int e = 0; e < 8; ++e) {
        float xv = (float)kv[e];
        ss += xv * xv;
        int d = h * 32 + i * 8 + e;
        Vt[d * 128 + (j ^ ((d & 7) << 3))] = vv4[e];
      }
      int ch = h * 4 + i;
      *(f16x8*)(&Kl[j * 64 + ((ch ^ (j & 7)) * 8)]) = kv;
    }
    partial[tid] = ss;
  }
  __syncthreads();
  if (tid < 128)
    rsqs[tid] = rsqrtf(fmaxf(partial[tid * 2] + partial[tid * 2 + 1], 1e-12f));
  __syncthreads();

  const int q0 = wid * 16;
  f32x4 acc[8];
  #pragma unroll
  for (int t = 0; t < 8; ++t) acc[t] = (f32x4){0.f, 0.f, 0.f, 0.f};
  f16x8 aq[2];
  #pragma unroll
  for (int ks = 0; ks < 2; ++ks)
    aq[ks] = *(const f16x8*)&Kl[(q0 + fr) * 64 + (((ks * 4 + g) ^ (fr & 7)) * 8)];
  #pragma unroll
  for (int t = 0; t < 8; ++t) {
    #pragma unroll
    for (int ks = 0; ks < 2; ++ks) {
      f16x8 bk = *(const f16x8*)&Kl[(t * 16 + fr) * 64 + (((ks * 4 + g) ^ (fr & 7)) * 8)];
      acc[t] = __builtin_amdgcn_mfma_f32_16x16x32_f16(aq[ks], bk, acc[t], 0, 0, 0);
    }
  }

  float sc[8][4];
  int pq[4];
  #pragma unroll
  for (int r = 0; r < 4; ++r) pq[r] = posl[q0 + g * 4 + r];
  #pragma unroll
  for (int t = 0; t < 8; ++t) {
    float rs = rsqs[t * 16 + fr] * 0.125f;
    int pk = posl[t * 16 + fr];
    #pragma unroll
    for (int r = 0; r < 4; ++r) {
      float v_ = acc[t][r] * rs;
      if (pq[r] == pk) v_ += -1e5f;
      sc[t][r] = v_;
    }
  }
  float lsef[4];
  #pragma unroll
  for (int r = 0; r < 4; ++r) {
    float m = sc[0][r];
    #pragma unroll
    for (int t = 1; t < 8; ++t) m = fmaxf(m, sc[t][r]);
    #pragma unroll
    for (int off = 1; off < 16; off <<= 1) m = fmaxf(m, __shfl_xor(m, off, 64));
    float s = 0.f;
    #pragma unroll
    for (int t = 0; t < 8; ++t) { float e = __expf(sc[t][r] - m); sc[t][r] = e; s += e; }
    #pragma unroll
    for (int off = 1; off < 16; off <<= 1) s += __shfl_xor(s, off, 64);
    lsef[r] = m + __logf(s);
    float f = 1.0f / s;
    #pragma unroll
    for (int t = 0; t < 8; ++t) sc[t][r] *= f;
  }

  #pragma unroll
  for (int t = 0; t < 8; ++t)
    #pragma unroll
    for (int r = 0; r < 4; ++r) {
      int q = q0 + g * 4 + r;
      Pl[q * 128 + ((t * 16 + fr) ^ ((q & 7) << 3))] = (_Float16)sc[t][r];
    }
  const int rr = c >> 6;
  if (fr == 0) {
    #pragma unroll
    for (int r = 0; r < 4; ++r) {
      int q = q0 + g * 4 + r;
      logits[((size_t)n * 2 + rr) * L_SEQ + posl[q]] = lsef[r];
    }
  }

  f32x4 acc2[4];
  #pragma unroll
  for (int td = 0; td < 4; ++td) acc2[td] = (f32x4){0.f, 0.f, 0.f, 0.f};
  #pragma unroll
  for (int s = 0; s < 4; ++s) {
    f16x8 ap = *(const f16x8*)&Pl[(q0 + fr) * 128 + (((s * 4 + g) ^ (fr & 7)) * 8)];
    #pragma unroll
    for (int td = 0; td < 4; ++td) {
      f16x8 bv = *(const f16x8*)&Vt[(td * 16 + fr) * 128 + (((s * 4 + g) ^ (fr & 7)) * 8)];
      acc2[td] = __builtin_amdgcn_mfma_f32_16x16x32_f16(ap, bv, acc2[td], 0, 0, 0);
    }
  }
  #pragma unroll
  for (int r = 0; r < 4; ++r) {
    int q = q0 + g * 4 + r;
    size_t base = (((size_t)n * 2 + rr) * L_SEQ + posl[q]) * 64;
    #pragma unroll
    for (int td = 0; td < 4; ++td)
      o[base + td * 16 + fr] = (_Float16)acc2[td][r];
  }
}

// ---------------- combine hash rounds -> f16 att [8192][1024] ----------------
__global__ __launch_bounds__(256)
void lsh_combine(const __half* __restrict__ o, const float* __restrict__ logits,
                 _Float16* __restrict__ attf) {
  size_t gid = (size_t)blockIdx.x * 256 + threadIdx.x;
  int q4 = (int)(gid & 15);
  size_t nl = gid >> 4;
  int n = (int)(nl >> 12), l = (int)(nl & 4095);
  float l0 = logits[((size_t)n * 2 + 0) * L_SEQ + l];
  float l1 = logits[((size_t)n * 2 + 1) * L_SEQ + l];
  float m = fmaxf(l0, l1);
  float e0 = __expf(l0 - m), e1 = __expf(l1 - m);
  float inv = 1.0f / (e0 + e1);
  float w0 = e0 * inv, w1 = e1 * inv;
  const __half2* r0 = (const __half2*)(o + (((size_t)n * 2 + 0) * L_SEQ + l) * 64) + q4 * 2;
  const __half2* r1 = (const __half2*)(o + (((size_t)n * 2 + 1) * L_SEQ + l) * 64) + q4 * 2;
  float2 a0 = __half22float2(r0[0]), a1 = __half22float2(r0[1]);
  float2 b0 = __half22float2(r1[0]), b1 = __half22float2(r1[1]);
  f16x4 res;
  res[0] = (_Float16)(w0 * a0.x + w1 * b0.x);
  res[1] = (_Float16)(w0 * a0.y + w1 * b0.y);
  res[2] = (_Float16)(w0 * a1.x + w1 * b1.x);
  res[3] = (_Float16)(w0 * a1.y + w1 * b1.y);
  int bb = n >> 4, h = n & 15;
  *(f16x4*)(attf + ((size_t)bb * L_SEQ + l) * 1024 + h * 64 + q4 * 4) = res;
}

extern "C" void kernel_launch(void* const* d_in, const int* in_sizes, int n_in,
                              void* d_out, int out_size, void* d_ws, size_t ws_size,
                              hipStream_t stream) {
  const float* x   = (const float*)d_in[0];
  const float* Wqk = (const float*)d_in[2];
  const float* Wv  = (const float*)d_in[3];
  const float* Wo  = (const float*)d_in[4];
  const float* rot = (const float*)d_in[5];
  float* out = (float*)d_out;
  char* ws = (char*)d_ws;

  _Float16*     qkh    = (_Float16*)(ws + 0);                 // 16 MB
  _Float16*     vh     = (_Float16*)(ws + 16777216ull);       // 16 MB
  _Float16*     xh     = (_Float16*)(ws + 33554432ull);       // 16 MB (dead after gemms)
  _Float16*     attf   = (_Float16*)(ws + 33554432ull);       // overlays xh
  _Float16*     o      = (_Float16*)(ws + 50331648ull);       // 32 MB (attn output)
  // pre-attn fixup scratch overlaying the o region:
  unsigned int* lists  = (unsigned int*)(ws + 50331648ull);   // 96 KB (16 x 1536)
  unsigned int* cntp   = (unsigned int*)(ws + 50429952ull);   // 64 B
  float*        qkfixp = (float*)(ws + 50528256ull);          // 24 MB (4 K-chunks)
  float*        logits = (float*)(ws + 83886080ull);          // 1 MB
  unsigned int* st     = (unsigned int*)(ws + 84934656ull);   // 1 MB
  unsigned char* bucket = (unsigned char*)(ws + 85983232ull); // 256 KB
  _Float16*     WqkT   = (_Float16*)(ws + 86245376ull);       // 2 MB
  _Float16*     WvT    = (_Float16*)(ws + 88342528ull);       // 2 MB
  _Float16*     WoT    = (_Float16*)(ws + 90439680ull);       // 2 MB
  _Float16*     rotT   = (_Float16*)(ws + 92536832ull);       // 8 KB

  dim3 gb(256);
  dim3 gemmGrid(512);

  hipMemsetAsync(cntp, 0, 16 * sizeof(unsigned int), stream);
  cvt_f16<<<dim3(8192), gb, 0, stream>>>(x, xh);
  cvt_tr_f16<<<dim3(32, 32), gb, 0, stream>>>(Wqk, WqkT);
  cvt_tr_f16<<<dim3(32, 32), gb, 0, stream>>>(Wv, WvT);
  cvt_tr_f16<<<dim3(32, 32), gb, 0, stream>>>(Wo, WoT);
  cvt_rotT<<<dim3(1), gb, 0, stream>>>(rot, rotT);

  gemm_f16<1><<<gemmGrid, gb, 0, stream>>>(xh, WqkT, (float*)qkh, 8192, 1024, 1024);
  gemm_f16<1><<<gemmGrid, gb, 0, stream>>>(xh, WvT, (float*)vh, 8192, 1024, 1024);

  lsh_hash3<<<dim3(1024), gb, 0, stream>>>(qkh, rotT, bucket, lists, cntp);
  lsh_fix_gemm<<<dim3(16, 24, 4), gb, 0, stream>>>(x, Wqk, lists, cntp, qkfixp);
  lsh_fix_rot<<<dim3(256), gb, 0, stream>>>(qkfixp, rot, lists, cntp, bucket);
  lsh_sort<<<dim3(64), gb, 0, stream>>>(bucket, st);
  lsh_attn_mfma<<<dim3(128, 32), gb, 0, stream>>>(qkh, vh, st, o, logits);
  lsh_combine<<<dim3(8192), gb, 0, stream>>>((const __half*)o, logits, attf);

  gemm_f16<0><<<gemmGrid, gb, 0, stream>>>(attf, WoT, out, 8192, 1024, 1024);
}

// Round 18
// 227.563 us; speedup vs baseline: 1.0492x; 1.0058x over previous
//
#include <hip/hip_runtime.h>
#include <hip/hip_fp16.h>

#define L_SEQ 4096
#define THR_GAP 0.08f
#define FIX_CAP 1536

typedef _Float16 f16x8 __attribute__((ext_vector_type(8)));
typedef _Float16 f16x4 __attribute__((ext_vector_type(4)));
typedef float f32x4 __attribute__((ext_vector_type(4)));

typedef __attribute__((address_space(3))) void lds_void;
typedef __attribute__((address_space(1))) void glob_void;
__device__ __forceinline__ void gload16(const _Float16* g, _Float16* l) {
  __builtin_amdgcn_global_load_lds((const glob_void*)g, (lds_void*)l, 16, 0, 0);
}

// ---------------- converts ----------------
__global__ __launch_bounds__(256)
void cvt_f16(const float* __restrict__ in, _Float16* __restrict__ out_) {
  int i = blockIdx.x * 256 + threadIdx.x;
  float4 v = ((const float4*)in)[i];
  f16x4 h;
  h[0] = (_Float16)v.x; h[1] = (_Float16)v.y;
  h[2] = (_Float16)v.z; h[3] = (_Float16)v.w;
  *(f16x4*)(out_ + (size_t)i * 4) = h;
}

__global__ __launch_bounds__(256)
void cvt_tr_f16(const float* __restrict__ W, _Float16* __restrict__ WT) {
  __shared__ _Float16 tile[32][33];
  const int bx = blockIdx.x * 32, by = blockIdx.y * 32;
  const int tx = threadIdx.x & 31, ty = threadIdx.x >> 5;
  #pragma unroll
  for (int i = ty; i < 32; i += 8)
    tile[i][tx] = (_Float16)W[(size_t)(by + i) * 1024 + bx + tx];
  __syncthreads();
  #pragma unroll
  for (int i = ty; i < 32; i += 8)
    WT[(size_t)(bx + i) * 1024 + by + tx] = tile[tx][i];
}

// rotT_f16[c][d] = rot[d][c],  c = nh*32+rb, 64x64
__global__ __launch_bounds__(256)
void cvt_rotT(const float* __restrict__ rot, _Float16* __restrict__ rotT) {
  const int tid = threadIdx.x;
  const int c = tid >> 2, d0 = (tid & 3) * 16;
  #pragma unroll
  for (int k = 0; k < 16; ++k)
    rotT[c * 64 + d0 + k] = (_Float16)rot[(d0 + k) * 64 + c];
}

// ---------------- f16 MFMA GEMM, dbuf + counted vmcnt: C = A * BT^T ----------------
// MODE 0: C row-major f32; MODE 1: scatter f16 to [n][l][d]
template<int MODE>
__global__ __launch_bounds__(256)
void gemm_f16(const _Float16* __restrict__ A, const _Float16* __restrict__ BT,
              float* __restrict__ C, int M, int K, int Nn) {
  __shared__ _Float16 As[2][128 * 64];
  __shared__ _Float16 Bs[2][128 * 64];
  const int tid = threadIdx.x;
  const int lane = tid & 63, wid = tid >> 6;
  const int wr = wid >> 1, wc = wid & 1;
  const int f = blockIdx.x;
  const int u = (f & 7) * 64 + (f >> 3);
  const int row0 = (u >> 3) * 128, col0 = (u & 7) * 128;

  f32x4 acc[4][4];
  #pragma unroll
  for (int i = 0; i < 4; ++i)
    #pragma unroll
    for (int j = 0; j < 4; ++j)
      acc[i][j] = (f32x4){0.f, 0.f, 0.f, 0.f};

  const int srow = (lane >> 3);
  const int scol = ((lane & 7) ^ srow) * 8;
  const _Float16* ga = A + (size_t)(row0 + wid * 32 + srow) * K + scol;
  const _Float16* gb = BT + (size_t)(col0 + wid * 32 + srow) * K + scol;
  const int lbase = (wid * 32) * 64;
  const int fr = lane & 15, g = lane >> 4;

#define STAGE_F16(buf, k0) do {                                          \
    _Pragma("unroll")                                                    \
    for (int i_ = 0; i_ < 4; ++i_) {                                     \
      gload16(ga + (k0) + (size_t)i_ * 8 * K, &As[buf][lbase + i_ * 8 * 64]); \
      gload16(gb + (k0) + (size_t)i_ * 8 * K, &Bs[buf][lbase + i_ * 8 * 64]); \
    }                                                                    \
  } while (0)

  STAGE_F16(0, 0);

  const int NT = K / 64;
  for (int t = 0; t < NT; ++t) {
    const int cur = t & 1, nxt = cur ^ 1;
    if (t + 1 < NT) {
      STAGE_F16(nxt, (size_t)(t + 1) * 64);
      asm volatile("s_waitcnt vmcnt(8)" ::: "memory");
    } else {
      asm volatile("s_waitcnt vmcnt(0)" ::: "memory");
    }
    __builtin_amdgcn_s_barrier();
    __builtin_amdgcn_sched_barrier(0);

    f16x8 af[4][2], bf[4][2];
    #pragma unroll
    for (int fi = 0; fi < 4; ++fi) {
      const int ra = (wr * 64 + fi * 16 + fr) * 64;
      const int rb = (wc * 64 + fi * 16 + fr) * 64;
      #pragma unroll
      for (int ks = 0; ks < 2; ++ks) {
        const int ko = (ks * 32 + g * 8) ^ ((fr & 7) * 8);
        af[fi][ks] = *(const f16x8*)(&As[cur][ra + ko]);
        bf[fi][ks] = *(const f16x8*)(&Bs[cur][rb + ko]);
      }
    }
    #pragma unroll
    for (int ks = 0; ks < 2; ++ks)
      #pragma unroll
      for (int fi = 0; fi < 4; ++fi)
        #pragma unroll
        for (int fj = 0; fj < 4; ++fj)
          acc[fi][fj] = __builtin_amdgcn_mfma_f32_16x16x32_f16(
              af[fi][ks], bf[fj][ks], acc[fi][fj], 0, 0, 0);
    __builtin_amdgcn_s_barrier();
    __builtin_amdgcn_sched_barrier(0);
  }
#undef STAGE_F16

  _Float16* Ch = (_Float16*)C;
  #pragma unroll
  for (int fi = 0; fi < 4; ++fi) {
    #pragma unroll
    for (int fj = 0; fj < 4; ++fj) {
      const int col = col0 + wc * 64 + fj * 16 + fr;
      #pragma unroll
      for (int r = 0; r < 4; ++r) {
        const int row = row0 + wr * 64 + fi * 16 + g * 4 + r;
        if (MODE == 0) {
          C[(size_t)row * Nn + col] = acc[fi][fj][r];
        } else {
          int b = row >> 12, l = row & 4095;
          int h = col >> 6, d = col & 63;
          Ch[(((size_t)(b * 16 + h) * L_SEQ) + l) * 64 + d] = (_Float16)acc[fi][fj][r];
        }
      }
    }
  }
}

// ---------------- MFMA LSH hashing: coalesced LDS staging + tree top-2 ----------------
// block = 4 waves; wave handles 32 consecutive tokens of batch n.
__global__ __launch_bounds__(256, 2)
void lsh_hash3(const _Float16* __restrict__ qkh, const _Float16* __restrict__ rotT,
               unsigned char* __restrict__ bucket,
               unsigned int* __restrict__ lists, unsigned int* __restrict__ cnt) {
  __shared__ _Float16 qt[4][32 * 64];   // wave-private staged qk tile (chunk-swizzled)
  __shared__ float buf[4][32][65];      // wave-private transpose tile [token][rot-col]
  const int tid = threadIdx.x, lane = tid & 63, wv = tid >> 6;
  const int fr = lane & 15, g = lane >> 4;
  const int bid = blockIdx.x;               // 1024
  const int n = bid >> 5;
  const int l0 = (bid & 31) * 128 + wv * 32;
  const int h = n & 15;

  // ---- coalesced stage: 4 KB tile, source pre-swizzled (rule 21, gemm pattern) ----
  // lane covers token (l>>3) of the 8-token stripe, chunk (l&7)^(l>>3)
  {
    const _Float16* qsrc = qkh + ((size_t)n * L_SEQ + l0 + (lane >> 3)) * 64
                         + (((lane & 7) ^ (lane >> 3)) * 8);
    #pragma unroll
    for (int i = 0; i < 4; ++i)
      gload16(qsrc + (size_t)i * 8 * 64, &qt[wv][i * 512]);
  }

  // B fragments meanwhile (broadcast, L2-hot): rotT row c = nh*32+rb, k = d
  f16x8 bf[4][2];
  #pragma unroll
  for (int fj = 0; fj < 4; ++fj)
    #pragma unroll
    for (int ks = 0; ks < 2; ++ks)
      bf[fj][ks] = *(const f16x8*)&rotT[(fj * 16 + fr) * 64 + ks * 32 + g * 8];

  asm volatile("s_waitcnt vmcnt(0)" ::: "memory");   // wave-private tile resident
  __builtin_amdgcn_sched_barrier(0);

  f32x4 acc[2][4];
  #pragma unroll
  for (int i = 0; i < 2; ++i)
    #pragma unroll
    for (int j = 0; j < 4; ++j)
      acc[i][j] = (f32x4){0.f, 0.f, 0.f, 0.f};

  // A fragments from LDS with the matching read swizzle (2-way max = free)
  #pragma unroll
  for (int fi = 0; fi < 2; ++fi) {
    const int row = fi * 16 + fr;
    f16x8 a0 = *(const f16x8*)&qt[wv][row * 64 + ((g ^ (row & 7)) * 8)];
    f16x8 a1 = *(const f16x8*)&qt[wv][row * 64 + (((4 + g) ^ (row & 7)) * 8)];
    #pragma unroll
    for (int fj = 0; fj < 4; ++fj) {
      acc[fi][fj] = __builtin_amdgcn_mfma_f32_16x16x32_f16(a0, bf[fj][0], acc[fi][fj], 0, 0, 0);
      acc[fi][fj] = __builtin_amdgcn_mfma_f32_16x16x32_f16(a1, bf[fj][1], acc[fi][fj], 0, 0, 0);
    }
  }

  // transpose to LDS: row = token-in-wave (0..31), col = rotation output (0..63)
  #pragma unroll
  for (int fi = 0; fi < 2; ++fi)
    #pragma unroll
    for (int fj = 0; fj < 4; ++fj)
      #pragma unroll
      for (int r = 0; r < 4; ++r)
        buf[wv][fi * 16 + g * 4 + r][fj * 16 + fr] = acc[fi][fj][r];

  // lane = (token, round); branchless tree top-2 over [v, -v]
  const int tok = lane & 31, nh = lane >> 5;
  float v[32];
  #pragma unroll
  for (int j = 0; j < 32; ++j) v[j] = buf[wv][tok][nh * 32 + j];
  float maxv = v[0], minv = v[0];
  #pragma unroll
  for (int j = 1; j < 32; ++j) { maxv = fmaxf(maxv, v[j]); minv = fminf(minv, v[j]); }
  float m1 = fmaxf(maxv, -minv);
  int idx = 64;
  #pragma unroll
  for (int j = 0; j < 32; ++j) idx = min(idx, (v[j] == m1) ? j : 64);
  #pragma unroll
  for (int j = 0; j < 32; ++j) idx = min(idx, (-v[j] == m1) ? 32 + j : 64);
  float m2 = -3.0e38f;
  #pragma unroll
  for (int j = 0; j < 32; ++j) m2 = fmaxf(m2, (j == idx) ? -3.0e38f : v[j]);
  #pragma unroll
  for (int j = 0; j < 32; ++j) m2 = fmaxf(m2, ((32 + j) == idx) ? -3.0e38f : -v[j]);
  const float gap = m1 - m2;
  const int obi = __shfl_xor(idx, 32, 64);
  const float ogap = __shfl_xor(gap, 32, 64);
  if (nh == 0) {
    const int t = l0 + tok;
    bucket[((size_t)n * 2 + 0) * L_SEQ + t] = (unsigned char)idx;
    bucket[((size_t)n * 2 + 1) * L_SEQ + t] = (unsigned char)obi;
    if (fminf(gap, ogap) < THR_GAP) {
      unsigned int pos = atomicAdd(&cnt[h], 1u);
      if (pos < FIX_CAP)
        lists[(size_t)h * FIX_CAP + pos] = ((unsigned int)n << 12) | (unsigned int)t;
    }
  }
}

// ---------------- fixup phase A: K-split skinny GEMM partials ----------------
__global__ __launch_bounds__(256)
void lsh_fix_gemm(const float* __restrict__ x, const float* __restrict__ Wqk,
                  const unsigned int* __restrict__ lists,
                  const unsigned int* __restrict__ cnt,
                  float* __restrict__ qkfixp) {
  __shared__ float As[32][65];
  __shared__ float Bs[32][64];
  __shared__ int rowIdx[64];
  const int h = blockIdx.x;
  const int rt = blockIdx.y;
  const int ks = blockIdx.z;
  const unsigned int nfix = min(cnt[h], (unsigned int)FIX_CAP);
  if ((unsigned int)(rt * 64) >= nfix) return;
  const int tid = threadIdx.x;
  if (tid < 64) {
    unsigned int i = (unsigned int)(rt * 64 + tid);
    if (i >= nfix) i = nfix - 1;
    unsigned int ent = lists[(size_t)h * FIX_CAP + i];
    rowIdx[tid] = (int)((ent >> 12) >> 4) * 4096 + (int)(ent & 4095);
  }
  __syncthreads();
  float acc[4][4] = {{0.f}};
  const int tx = tid & 15, ty = tid >> 4;
  const int am = tid >> 2, ae = (tid & 3) * 8;
  const int be = tid >> 3, bd = (tid & 7) * 8;
  const size_t arow = (size_t)rowIdx[am] * 1024;
  const int kbeg = ks * 256, kend = kbeg + 256;

  float4 ra0, ra1, rb0, rb1;
  {
    const float* xr = x + arow + kbeg + ae;
    ra0 = *(const float4*)xr; ra1 = *(const float4*)(xr + 4);
    const float* wr = Wqk + (size_t)(kbeg + be) * 1024 + h * 64 + bd;
    rb0 = *(const float4*)wr; rb1 = *(const float4*)(wr + 4);
  }
  for (int k0 = kbeg; k0 < kend; k0 += 32) {
    As[ae + 0][am] = ra0.x; As[ae + 1][am] = ra0.y;
    As[ae + 2][am] = ra0.z; As[ae + 3][am] = ra0.w;
    As[ae + 4][am] = ra1.x; As[ae + 5][am] = ra1.y;
    As[ae + 6][am] = ra1.z; As[ae + 7][am] = ra1.w;
    *(float4*)&Bs[be][bd] = rb0;
    *(float4*)&Bs[be][bd + 4] = rb1;
    __syncthreads();
    if (k0 + 32 < kend) {
      const float* xr = x + arow + (k0 + 32) + ae;
      ra0 = *(const float4*)xr; ra1 = *(const float4*)(xr + 4);
      const float* wr = Wqk + (size_t)(k0 + 32 + be) * 1024 + h * 64 + bd;
      rb0 = *(const float4*)wr; rb1 = *(const float4*)(wr + 4);
    }
    #pragma unroll
    for (int k = 0; k < 32; ++k) {
      float a[4], b[4];
      #pragma unroll
      for (int j = 0; j < 4; ++j) a[j] = As[k][ty * 4 + j];
      #pragma unroll
      for (int j = 0; j < 4; ++j) b[j] = Bs[k][tx * 4 + j];
      #pragma unroll
      for (int i = 0; i < 4; ++i)
        #pragma unroll
        for (int j = 0; j < 4; ++j)
          acc[i][j] += a[i] * b[j];
    }
    __syncthreads();
  }
  #pragma unroll
  for (int i = 0; i < 4; ++i) {
    int m = rt * 64 + ty * 4 + i;
    float* dst = qkfixp + (((size_t)ks * 16 + h) * FIX_CAP + m) * 64 + tx * 4;
    dst[0] = acc[i][0]; dst[1] = acc[i][1];
    dst[2] = acc[i][2]; dst[3] = acc[i][3];
  }
}

// ---------------- fixup phase B: sum K-partials, rotations, exact argmax --------
__global__ __launch_bounds__(256)
void lsh_fix_rot(const float* __restrict__ qkfixp, const float* __restrict__ rot,
                 const unsigned int* __restrict__ lists,
                 const unsigned int* __restrict__ cnt,
                 unsigned char* __restrict__ bucket) {
  __shared__ float rotL[4096];
  __shared__ float qkL[4][64];
  const int h = blockIdx.x & 15;
  const int bg = blockIdx.x >> 4;
  const int tid = threadIdx.x, lane = tid & 63, wv = tid >> 6;
  for (int i = tid; i < 4096; i += 256) rotL[i] = rot[i];
  __syncthreads();
  const unsigned int nfix = min(cnt[h], (unsigned int)FIX_CAP);
  for (unsigned int i = (unsigned int)(bg * 4 + wv); i < nfix; i += 64) {
    unsigned int ent = lists[(size_t)h * FIX_CAP + i];
    const int nn = (int)(ent >> 12), ll = (int)(ent & 4095);
    float s0 = qkfixp[(((size_t)0 * 16 + h) * FIX_CAP + i) * 64 + lane];
    float s1 = qkfixp[(((size_t)1 * 16 + h) * FIX_CAP + i) * 64 + lane];
    float s2 = qkfixp[(((size_t)2 * 16 + h) * FIX_CAP + i) * 64 + lane];
    float s3 = qkfixp[(((size_t)3 * 16 + h) * FIX_CAP + i) * 64 + lane];
    qkL[wv][lane] = ((s0 + s1) + s2) + s3;
    asm volatile("s_waitcnt vmcnt(0) lgkmcnt(0)" ::: "memory");
    float v = 0.f;
    #pragma unroll 16
    for (int d = 0; d < 64; ++d)
      v += qkL[wv][d] * rotL[d * 64 + lane];
    const int r = lane & 31;
    float vneg = -v;
    float bv; int bi;
    if (vneg > v) { bv = vneg; bi = 32 + r; } else { bv = v; bi = r; }
    #pragma unroll
    for (int off = 1; off < 32; off <<= 1) {
      float ov = __shfl_xor(bv, off, 64);
      int oi = __shfl_xor(bi, off, 64);
      if (ov > bv || (ov == bv && oi < bi)) { bv = ov; bi = oi; }
    }
    if (r == 0) {
      int hr = lane >> 5;
      bucket[((size_t)(nn * 2 + hr)) * L_SEQ + ll] = (unsigned char)bi;
    }
  }
}

// ---------------- parallel stable counting sort per (n, round) ----------------
__global__ __launch_bounds__(256)
void lsh_sort(const unsigned char* __restrict__ bucket, unsigned int* __restrict__ st) {
  __shared__ unsigned short cnt[64][257];
  __shared__ unsigned int bstart[64];
  __shared__ unsigned char bkt[4096];
  const int nr = blockIdx.x;
  const int tid = threadIdx.x;
  const unsigned char* bsrc = bucket + (size_t)nr * L_SEQ;
  for (int i = tid; i < 1024; i += 256)
    ((unsigned int*)bkt)[i] = ((const unsigned int*)bsrc)[i];
  #pragma unroll
  for (int b = 0; b < 64; ++b) cnt[b][tid] = 0;
  __syncthreads();
  uint4 wv = ((const uint4*)bkt)[tid];
  unsigned int wsg[4] = {wv.x, wv.y, wv.z, wv.w};
  #pragma unroll
  for (int k = 0; k < 16; ++k) {
    int b = (wsg[k >> 2] >> ((k & 3) * 8)) & 63;
    cnt[b][tid]++;
  }
  __syncthreads();
  if (tid < 64) {
    const int b = tid;
    unsigned int run = 0;
    for (int t = 0; t < 256; ++t) {
      unsigned int c = cnt[b][t];
      cnt[b][t] = (unsigned short)run;
      run += c;
    }
    unsigned int incl = run;
    #pragma unroll
    for (int off = 1; off < 64; off <<= 1) {
      unsigned int up = (unsigned int)__shfl_up((int)incl, off);
      if (tid >= off) incl += up;
    }
    bstart[b] = incl - run;
  }
  __syncthreads();
  const int n = nr >> 1, r = nr & 1;
  unsigned int* dst = st + (size_t)n * 8192 + (size_t)r * 4096;
  #pragma unroll
  for (int k = 0; k < 16; ++k) {
    int b = (wsg[k >> 2] >> ((k & 3) * 8)) & 63;
    unsigned int idx = bstart[b] + cnt[b][tid];
    cnt[b][tid]++;
    dst[idx] = (unsigned int)(tid * 16 + k);
  }
}

// ---------------- MFMA chunked local attention (f16 qk gather) ----------------
__global__ __launch_bounds__(256)
void lsh_attn_mfma(const _Float16* __restrict__ qkh, const _Float16* __restrict__ vh,
                   const unsigned int* __restrict__ st,
                   _Float16* __restrict__ o, float* __restrict__ logits) {
  __shared__ _Float16 Kl[128 * 64];
  __shared__ _Float16 Vt[64 * 128];
  __shared__ _Float16 Pl[64 * 128];
  __shared__ float rsqs[128];
  __shared__ float partial[256];
  __shared__ int posl[128];

  const int tid = threadIdx.x;
  const int lane = tid & 63, wid = tid >> 6;
  const int fr = lane & 15, g = lane >> 4;
  const int c = blockIdx.x, n = blockIdx.y;
  const int cprev = (c + 127) & 127;

  if (tid < 128) {
    int p = (tid < 64) ? (c * 64 + tid) : (cprev * 64 + (tid - 64));
    posl[tid] = (int)st[(size_t)n * 8192 + p];
  }
  __syncthreads();

  {
    const int j = tid >> 1, h = tid & 1;
    const int gpos = posl[j];
    const f16x8* srcK = (const f16x8*)(qkh + ((size_t)n * L_SEQ + gpos) * 64 + h * 32);
    const f16x8* srcV = (const f16x8*)(vh + ((size_t)n * L_SEQ + gpos) * 64 + h * 32);
    float ss = 0.f;
    #pragma unroll
    for (int i = 0; i < 4; ++i) {
      f16x8 kv = srcK[i];
      f16x8 vv4 = srcV[i];
      #pragma unroll
      for (int e = 0; e < 8; ++e) {
        float xv = (float)kv[e];
        ss += xv * xv;
        int d = h * 32 + i * 8 + e;
        Vt[d * 128 + (j ^ ((d & 7) << 3))] = vv4[e];
      }
      int ch = h * 4 + i;
      *(f16x8*)(&Kl[j * 64 + ((ch ^ (j & 7)) * 8)]) = kv;
    }
    partial[tid] = ss;
  }
  __syncthreads();
  if (tid < 128)
    rsqs[tid] = rsqrtf(fmaxf(partial[tid * 2] + partial[tid * 2 + 1], 1e-12f));
  __syncthreads();

  const int q0 = wid * 16;
  f32x4 acc[8];
  #pragma unroll
  for (int t = 0; t < 8; ++t) acc[t] = (f32x4){0.f, 0.f, 0.f, 0.f};
  f16x8 aq[2];
  #pragma unroll
  for (int ks = 0; ks < 2; ++ks)
    aq[ks] = *(const f16x8*)&Kl[(q0 + fr) * 64 + (((ks * 4 + g) ^ (fr & 7)) * 8)];
  #pragma unroll
  for (int t = 0; t < 8; ++t) {
    #pragma unroll
    for (int ks = 0; ks < 2; ++ks) {
      f16x8 bk = *(const f16x8*)&Kl[(t * 16 + fr) * 64 + (((ks * 4 + g) ^ (fr & 7)) * 8)];
      acc[t] = __builtin_amdgcn_mfma_f32_16x16x32_f16(aq[ks], bk, acc[t], 0, 0, 0);
    }
  }

  float sc[8][4];
  int pq[4];
  #pragma unroll
  for (int r = 0; r < 4; ++r) pq[r] = posl[q0 + g * 4 + r];
  #pragma unroll
  for (int t = 0; t < 8; ++t) {
    float rs = rsqs[t * 16 + fr] * 0.125f;
    int pk = posl[t * 16 + fr];
    #pragma unroll
    for (int r = 0; r < 4; ++r) {
      float v_ = acc[t][r] * rs;
      if (pq[r] == pk) v_ += -1e5f;
      sc[t][r] = v_;
    }
  }
  float lsef[4];
  #pragma unroll
  for (int r = 0; r < 4; ++r) {
    float m = sc[0][r];
    #pragma unroll
    for (int t = 1; t < 8; ++t) m = fmaxf(m, sc[t][r]);
    #pragma unroll
    for (int off = 1; off < 16; off <<= 1) m = fmaxf(m, __shfl_xor(m, off, 64));
    float s = 0.f;
    #pragma unroll
    for (int t = 0; t < 8; ++t) { float e = __expf(sc[t][r] - m); sc[t][r] = e; s += e; }
    #pragma unroll
    for (int off = 1; off < 16; off <<= 1) s += __shfl_xor(s, off, 64);
    lsef[r] = m + __logf(s);
    float f = 1.0f / s;
    #pragma unroll
    for (int t = 0; t < 8; ++t) sc[t][r] *= f;
  }

  #pragma unroll
  for (int t = 0; t < 8; ++t)
    #pragma unroll
    for (int r = 0; r < 4; ++r) {
      int q = q0 + g * 4 + r;
      Pl[q * 128 + ((t * 16 + fr) ^ ((q & 7) << 3))] = (_Float16)sc[t][r];
    }
  const int rr = c >> 6;
  if (fr == 0) {
    #pragma unroll
    for (int r = 0; r < 4; ++r) {
      int q = q0 + g * 4 + r;
      logits[((size_t)n * 2 + rr) * L_SEQ + posl[q]] = lsef[r];
    }
  }

  f32x4 acc2[4];
  #pragma unroll
  for (int td = 0; td < 4; ++td) acc2[td] = (f32x4){0.f, 0.f, 0.f, 0.f};
  #pragma unroll
  for (int s = 0; s < 4; ++s) {
    f16x8 ap = *(const f16x8*)&Pl[(q0 + fr) * 128 + (((s * 4 + g) ^ (fr & 7)) * 8)];
    #pragma unroll
    for (int td = 0; td < 4; ++td) {
      f16x8 bv = *(const f16x8*)&Vt[(td * 16 + fr) * 128 + (((s * 4 + g) ^ (fr & 7)) * 8)];
      acc2[td] = __builtin_amdgcn_mfma_f32_16x16x32_f16(ap, bv, acc2[td], 0, 0, 0);
    }
  }
  #pragma unroll
  for (int r = 0; r < 4; ++r) {
    int q = q0 + g * 4 + r;
    size_t base = (((size_t)n * 2 + rr) * L_SEQ + posl[q]) * 64;
    #pragma unroll
    for (int td = 0; td < 4; ++td)
      o[base + td * 16 + fr] = (_Float16)acc2[td][r];
  }
}

// ---------------- combine hash rounds -> f16 att [8192][1024] ----------------
__global__ __launch_bounds__(256)
void lsh_combine(const __half* __restrict__ o, const float* __restrict__ logits,
                 _Float16* __restrict__ attf) {
  size_t gid = (size_t)blockIdx.x * 256 + threadIdx.x;
  int q4 = (int)(gid & 15);
  size_t nl = gid >> 4;
  int n = (int)(nl >> 12), l = (int)(nl & 4095);
  float l0 = logits[((size_t)n * 2 + 0) * L_SEQ + l];
  float l1 = logits[((size_t)n * 2 + 1) * L_SEQ + l];
  float m = fmaxf(l0, l1);
  float e0 = __expf(l0 - m), e1 = __expf(l1 - m);
  float inv = 1.0f / (e0 + e1);
  float w0 = e0 * inv, w1 = e1 * inv;
  const __half2* r0 = (const __half2*)(o + (((size_t)n * 2 + 0) * L_SEQ + l) * 64) + q4 * 2;
  const __half2* r1 = (const __half2*)(o + (((size_t)n * 2 + 1) * L_SEQ + l) * 64) + q4 * 2;
  float2 a0 = __half22float2(r0[0]), a1 = __half22float2(r0[1]);
  float2 b0 = __half22float2(r1[0]), b1 = __half22float2(r1[1]);
  f16x4 res;
  res[0] = (_Float16)(w0 * a0.x + w1 * b0.x);
  res[1] = (_Float16)(w0 * a0.y + w1 * b0.y);
  res[2] = (_Float16)(w0 * a1.x + w1 * b1.x);
  res[3] = (_Float16)(w0 * a1.y + w1 * b1.y);
  int bb = n >> 4, h = n & 15;
  *(f16x4*)(attf + ((size_t)bb * L_SEQ + l) * 1024 + h * 64 + q4 * 4) = res;
}

extern "C" void kernel_launch(void* const* d_in, const int* in_sizes, int n_in,
                              void* d_out, int out_size, void* d_ws, size_t ws_size,
                              hipStream_t stream) {
  const float* x   = (const float*)d_in[0];
  const float* Wqk = (const float*)d_in[2];
  const float* Wv  = (const float*)d_in[3];
  const float* Wo  = (const float*)d_in[4];
  const float* rot = (const float*)d_in[5];
  float* out = (float*)d_out;
  char* ws = (char*)d_ws;

  _Float16*     qkh    = (_Float16*)(ws + 0);                 // 16 MB
  _Float16*     vh     = (_Float16*)(ws + 16777216ull);       // 16 MB
  _Float16*     xh     = (_Float16*)(ws + 33554432ull);       // 16 MB (dead after gemms)
  _Float16*     attf   = (_Float16*)(ws + 33554432ull);       // overlays xh
  _Float16*     o      = (_Float16*)(ws + 50331648ull);       // 32 MB (attn output)
  // pre-attn fixup scratch overlaying the o region:
  unsigned int* lists  = (unsigned int*)(ws + 50331648ull);   // 96 KB (16 x 1536)
  unsigned int* cntp   = (unsigned int*)(ws + 50429952ull);   // 64 B
  float*        qkfixp = (float*)(ws + 50528256ull);          // 24 MB (4 K-chunks)
  float*        logits = (float*)(ws + 83886080ull);          // 1 MB
  unsigned int* st     = (unsigned int*)(ws + 84934656ull);   // 1 MB
  unsigned char* bucket = (unsigned char*)(ws + 85983232ull); // 256 KB
  _Float16*     WqkT   = (_Float16*)(ws + 86245376ull);       // 2 MB
  _Float16*     WvT    = (_Float16*)(ws + 88342528ull);       // 2 MB
  _Float16*     WoT    = (_Float16*)(ws + 90439680ull);       // 2 MB
  _Float16*     rotT   = (_Float16*)(ws + 92536832ull);       // 8 KB

  dim3 gb(256);
  dim3 gemmGrid(512);

  hipMemsetAsync(cntp, 0, 16 * sizeof(unsigned int), stream);
  cvt_f16<<<dim3(8192), gb, 0, stream>>>(x, xh);
  cvt_tr_f16<<<dim3(32, 32), gb, 0, stream>>>(Wqk, WqkT);
  cvt_tr_f16<<<dim3(32, 32), gb, 0, stream>>>(Wv, WvT);
  cvt_tr_f16<<<dim3(32, 32), gb, 0, stream>>>(Wo, WoT);
  cvt_rotT<<<dim3(1), gb, 0, stream>>>(rot, rotT);

  gemm_f16<1><<<gemmGrid, gb, 0, stream>>>(xh, WqkT, (float*)qkh, 8192, 1024, 1024);
  gemm_f16<1><<<gemmGrid, gb, 0, stream>>>(xh, WvT, (float*)vh, 8192, 1024, 1024);

  lsh_hash3<<<dim3(1024), gb, 0, stream>>>(qkh, rotT, bucket, lists, cntp);
  lsh_fix_gemm<<<dim3(16, 24, 4), gb, 0, stream>>>(x, Wqk, lists, cntp, qkfixp);
  lsh_fix_rot<<<dim3(256), gb, 0, stream>>>(qkfixp, rot, lists, cntp, bucket);
  lsh_sort<<<dim3(64), gb, 0, stream>>>(bucket, st);
  lsh_attn_mfma<<<dim3(128, 32), gb, 0, stream>>>(qkh, vh, st, o, logits);
  lsh_combine<<<dim3(8192), gb, 0, stream>>>((const __half*)o, logits, attf);

  gemm_f16<0><<<gemmGrid, gb, 0, stream>>>(attf, WoT, out, 8192, 1024, 1024);
}